// Round 17
// baseline (606.053 us; speedup 1.0000x reference)
//
#include <hip/hip_runtime.h>
#include <cstdint>
#include <cstddef>

constexpr int N_  = 20480;
constexpr int E_  = 163840;
constexpr int G_  = 512;
constexpr int D_  = 128;
constexpr int H_  = 4;
constexpr int R_  = 8;
constexpr int L_  = 4;
constexpr int HK_ = 512;   // H*D
constexpr int NPG_ = N_ / G_; // 40

typedef short short8 __attribute__((ext_vector_type(8)));
typedef float f32x4 __attribute__((ext_vector_type(4)));
typedef unsigned short u16;
typedef unsigned int u32;

__device__ inline u16 bfr(float f) {  // fp32 -> bf16 RNE
  u32 u = __builtin_bit_cast(u32, f);
  return (u16)((u + 0x7fffu + ((u >> 16) & 1u)) >> 16);
}
__device__ inline float bf2f(u32 lo16) { return __builtin_bit_cast(float, lo16 << 16); }
__device__ inline float lrelu(float v) { return v >= 0.f ? v : 0.2f * v; }

// ---------------- fused zero: countsR (RN) + countsN (N) ----------------
__global__ void k_zero2(int* __restrict__ cR, int* __restrict__ cN) {
  int i = blockIdx.x * blockDim.x + threadIdx.x;
  if (i < R_ * N_) cR[i] = 0;
  else if (i < R_ * N_ + N_) cN[i - R_ * N_] = 0;
}

// ---------------- fused count: rel-CSR + dst-CSR ----------------
__global__ void k_count_both(const int* __restrict__ dst, const int* __restrict__ et,
                             int* __restrict__ cR, int* __restrict__ cN) {
  int e = blockIdx.x * blockDim.x + threadIdx.x;
  if (e < E_) {
    int d = dst[e];
    atomicAdd(&cR[et[e] * N_ + d], 1);
    atomicAdd(&cN[d], 1);
  }
}

// ---------------- fused per-block sums ----------------
__global__ void k_bsum2(const int* __restrict__ cR, const int* __restrict__ cN,
                        int* __restrict__ bsumR, int* __restrict__ bsumN) {
  int b = blockIdx.x;
  const int* src = (b < 160) ? &cR[b * 1024] : &cN[(b - 160) * 1024];
  int t = threadIdx.x;
  const int4 v = *(const int4*)&src[t * 4];
  int s = v.x + v.y + v.z + v.w;
#pragma unroll
  for (int o = 32; o; o >>= 1) s += __shfl_down(s, o, 64);
  __shared__ int ws_[4];
  if ((t & 63) == 0) ws_[t >> 6] = s;
  __syncthreads();
  if (t == 0) {
    int tot = ws_[0] + ws_[1] + ws_[2] + ws_[3];
    if (b < 160) bsumR[b] = tot; else bsumN[b - 160] = tot;
  }
}

// ---------------- fused block-sum scan + totals + padBase (r6 lesson: totals MUST be written) ----------------
__global__ void k_bscan2(int* __restrict__ bsumR, int* __restrict__ bsumN,
                         int* __restrict__ totR, int* __restrict__ totN,
                         int* __restrict__ padBase) {
  __shared__ int shR[160];
  __shared__ int shN[20];
  int t = threadIdx.x;
  if (t < 160) shR[t] = bsumR[t];
  if (t < 20) shN[t] = bsumN[t];
  __syncthreads();
  if (t == 0) {
    int run = 0;
    for (int i = 0; i < 160; ++i) { int v = shR[i]; shR[i] = run; run += v; }
    totR[0] = run;   // = E
    int cum = 0;
    for (int r = 0; r < R_; ++r) {          // padBase from relation boundaries (block r*20)
      padBase[r] = cum;
      int lo = shR[r * 20];
      int hi = (r == R_ - 1) ? run : shR[(r + 1) * 20];
      cum += (hi - lo + 127) & ~127;
    }
    padBase[R_] = cum;
    int run2 = 0;
    for (int i = 0; i < 20; ++i) { int v = shN[i]; shN[i] = run2; run2 += v; }
    totN[0] = run2;  // = E
  }
  __syncthreads();
  if (t < 160) bsumR[t] = shR[t];
  if (t < 20) bsumN[t] = shN[t];
}

// ---------------- fused full scan write ----------------
__global__ void k_scan32(const int* __restrict__ cR, const int* __restrict__ cN,
                         const int* __restrict__ bsumR, const int* __restrict__ bsumN,
                         int* __restrict__ ipR, int* __restrict__ curR,
                         int* __restrict__ ipN, int* __restrict__ curN) {
  __shared__ int ts[256];
  int b = blockIdx.x;
  const int* c;
  int off0;
  int* indptr;
  int* cursor;
  int lb;
  if (b < 160) { c = cR; off0 = bsumR[b]; indptr = ipR; cursor = curR; lb = b; }
  else { c = cN; off0 = bsumN[b - 160]; indptr = ipN; cursor = curN; lb = b - 160; }
  int t = threadIdx.x;
  int base = lb * 1024 + t * 4;
  const int4 v = *(const int4*)&c[base];
  int s0 = v.x, s01 = v.x + v.y, s012 = s01 + v.z, s = s012 + v.w;
  ts[t] = s;
  __syncthreads();
#pragma unroll
  for (int o = 1; o < 256; o <<= 1) {
    int add = (t >= o) ? ts[t - o] : 0;
    __syncthreads();
    ts[t] += add;
    __syncthreads();
  }
  int off = off0 + (t ? ts[t - 1] : 0);
  int4 o4 = make_int4(off, off + s0, off + s01, off + s012);
  *(int4*)&indptr[base] = o4;
  *(int4*)&cursor[base] = o4;
}

// ---------------- fused scatter: rel slots (slotOf,srcR) + dst-CSR (esortD) ----------------
__global__ void k_scatter_both(const int* __restrict__ dst, const int* __restrict__ et,
                               const int* __restrict__ src, int* __restrict__ curR,
                               int* __restrict__ curN, int* __restrict__ slotOf,
                               int* __restrict__ srcR, int* __restrict__ esortD) {
  int e = blockIdx.x * blockDim.x + threadIdx.x;
  if (e < E_) {
    int d = dst[e];
    int p = atomicAdd(&curR[et[e] * N_ + d], 1);
    slotOf[e] = p;
    srcR[p] = src[e];
    int p2 = atomicAdd(&curN[d], 1);
    esortD[p2] = e;
  }
}

// ---------------- WQK for ALL layers: wave per (l,r,d) row ----------------
__global__ __launch_bounds__(256) void k_wqk_all(const float* __restrict__ W,
                                                 const float* __restrict__ Q,
                                                 const float* __restrict__ Km,
                                                 float* __restrict__ WQK) {
  int gw = (blockIdx.x * 256 + threadIdx.x) >> 6;  // 0..L*R*D-1 = 4095
  int lane = threadIdx.x & 63;
  int d = gw & 127, r = (gw >> 7) & 7, l = gw >> 10;
  const float* wrow = W + (((size_t)l * R_ + r) * D_ + d) * HK_;
  const float* Ql = Q + (size_t)l * HK_ * H_;
  const float* Kl = Km + (size_t)l * HK_ * H_;
  float acc[8] = {0.f, 0.f, 0.f, 0.f, 0.f, 0.f, 0.f, 0.f};
#pragma unroll
  for (int it = 0; it < 8; ++it) {
    int k = it * 64 + lane;
    float w = wrow[k];
    const float4 qv = *(const float4*)&Ql[k * 4];
    const float4 kv = *(const float4*)&Kl[k * 4];
    acc[0] += w * qv.x; acc[1] += w * qv.y; acc[2] += w * qv.z; acc[3] += w * qv.w;
    acc[4] += w * kv.x; acc[5] += w * kv.y; acc[6] += w * kv.z; acc[7] += w * kv.w;
  }
#pragma unroll
  for (int o = 32; o; o >>= 1)
#pragma unroll
    for (int j = 0; j < 8; ++j) acc[j] += __shfl_down(acc[j], o, 64);
  if (lane == 0) {
#pragma unroll
    for (int h = 0; h < 4; ++h) {
      WQK[((size_t)l * D_ + d) * 64 + r * 4 + h] = acc[h];
      WQK[((size_t)l * D_ + d) * 64 + 32 + r * 4 + h] = acc[4 + h];
    }
  }
}

// ---------------- fused embed + layer-0 q,k (32 nodes/block) ----------------
__global__ __launch_bounds__(256) void k_embed_qk(
    const int* __restrict__ xn, const float* __restrict__ emb,
    const float* __restrict__ WQK, float* __restrict__ x, u16* __restrict__ xb,
    float* __restrict__ q, float* __restrict__ kk) {
  __shared__ float xs[32][129];
  __shared__ float wq[128][64];
  __shared__ int xnl[32];
  const int t = threadIdx.x;
  const int n0 = blockIdx.x * 32;
  if (t < 32) xnl[t] = xn[n0 + t];
#pragma unroll
  for (int p = 0; p < 8; ++p) {
    int idx = t + p * 256;
    int row = idx >> 4, c4 = (idx & 15) * 4;
    *(float4*)&wq[row][c4] = *(const float4*)&WQK[row * 64 + c4];
  }
  __syncthreads();
#pragma unroll
  for (int p = 0; p < 16; ++p) {      // 4096 elems of x
    int idx = t + p * 256;
    int node = idx >> 7, d = idx & 127;
    float v = emb[xnl[node] * D_ + d];
    xs[node][d] = v;
    x[(size_t)(n0 + node) * D_ + d] = v;
    xb[(size_t)(n0 + node) * D_ + d] = bfr(v);
  }
  __syncthreads();
  const int node = t >> 3, cq = t & 7;
  float s[8];
#pragma unroll
  for (int j = 0; j < 8; ++j) s[j] = 0.f;
  for (int k = 0; k < 128; ++k) {
    float xv = xs[node][k];
#pragma unroll
    for (int j = 0; j < 8; ++j) s[j] = fmaf(xv, wq[k][cq * 8 + j], s[j]);
  }
#pragma unroll
  for (int j = 0; j < 8; ++j) {
    int c = cq * 8 + j;
    if (c < 32) q[(size_t)(n0 + node) * 32 + c] = s[j];
    else        kk[(size_t)(n0 + node) * 32 + (c - 32)] = s[j];
  }
}

// ---------------- fused attention softmax: wave per dst node, normalized aw out ----------------
__global__ __launch_bounds__(256) void k_attn(
    const int* __restrict__ ipN, const int* __restrict__ esD,
    const int* __restrict__ src, const int* __restrict__ et,
    const float* __restrict__ q, const float* __restrict__ kk,
    const int* __restrict__ slotOf, float* __restrict__ aw) {
  int n = blockIdx.x * 4 + (threadIdx.x >> 6);
  int lane = threadIdx.x & 63;
  int j0 = ipN[n], j1 = ipN[n + 1];
  int deg = j1 - j0;
  if (deg == 0) return;            // wave-uniform
  int h = lane & 3;
  if (deg <= 16) {                 // fast path (covers most nodes)
    int ei = lane >> 2;
    float a = -3.4e38f;
    int slot = 0;
    if (ei < deg) {
      int e = esD[j0 + ei];
      int r = et[e];
      slot = slotOf[e];
      a = lrelu(q[(size_t)n * 32 + r * 4 + h] + kk[(size_t)src[e] * 32 + r * 4 + h]);
    }
    float m = a;
#pragma unroll
    for (int o = 4; o < 64; o <<= 1) m = fmaxf(m, __shfl_xor(m, o, 64));
    float ex = (ei < deg) ? expf(a - m) : 0.f;
    float s = ex;
#pragma unroll
    for (int o = 4; o < 64; o <<= 1) s += __shfl_xor(s, o, 64);
    if (ei < deg) aw[(size_t)slot * 4 + h] = ex * (0.25f / (s + 1e-16f));
    return;
  }
  // general path (rare)
  int nch = (deg + 15) >> 4;
  float m = -3.4e38f;
  for (int c = 0; c < nch; ++c) {
    int ei = c * 16 + (lane >> 2);
    if (ei < deg) {
      int e = esD[j0 + ei];
      int r = et[e];
      float a = lrelu(q[(size_t)n * 32 + r * 4 + h] + kk[(size_t)src[e] * 32 + r * 4 + h]);
      m = fmaxf(m, a);
    }
  }
#pragma unroll
  for (int o = 4; o < 64; o <<= 1) m = fmaxf(m, __shfl_xor(m, o, 64));
  float s = 0.f;
  for (int c = 0; c < nch; ++c) {
    int ei = c * 16 + (lane >> 2);
    if (ei < deg) {
      int e = esD[j0 + ei];
      int r = et[e];
      float a = lrelu(q[(size_t)n * 32 + r * 4 + h] + kk[(size_t)src[e] * 32 + r * 4 + h]);
      float ex = expf(a - m);
      s += ex;
      aw[(size_t)slotOf[e] * 4 + h] = ex;
    }
  }
#pragma unroll
  for (int o = 4; o < 64; o <<= 1) s += __shfl_xor(s, o, 64);
  float inv = 0.25f / (s + 1e-16f);
  for (int c = 0; c < nch; ++c) {
    int ei = c * 16 + (lane >> 2);
    if (ei < deg) {
      int e = esD[j0 + ei];
      aw[(size_t)slotOf[e] * 4 + h] *= inv;
    }
  }
}

// W fp32 [L][R][D][HK] -> wt bf16 [L][R][HK][D]  (all layers, z = l*R+r)
__global__ void k_cvt_w_all(const float* __restrict__ W, u16* __restrict__ wt) {
  __shared__ u16 tile[64][65];
  const int z = blockIdx.z, k0 = blockIdx.y * 64, c0 = blockIdx.x * 64;
  const int t = threadIdx.x;
  const int tk = t >> 4, tc4 = (t & 15) * 4;
  const float* Wz = W + (size_t)z * D_ * HK_;
  u16* wz = wt + (size_t)z * HK_ * D_;
#pragma unroll
  for (int p = 0; p < 4; ++p) {
    int krow = tk + p * 16;
    const float4 v = *(const float4*)&Wz[(size_t)(k0 + krow) * HK_ + c0 + tc4];
    tile[tc4 + 0][krow] = bfr(v.x);
    tile[tc4 + 1][krow] = bfr(v.y);
    tile[tc4 + 2][krow] = bfr(v.z);
    tile[tc4 + 3][krow] = bfr(v.w);
  }
  __syncthreads();
#pragma unroll
  for (int p = 0; p < 4; ++p) {
    int crow = tk + p * 16;
    uint2 o;
    o.x = (u32)tile[crow][tc4 + 0] | ((u32)tile[crow][tc4 + 1] << 16);
    o.y = (u32)tile[crow][tc4 + 2] | ((u32)tile[crow][tc4 + 3] << 16);
    *(uint2*)&wz[(size_t)(c0 + crow) * D_ + k0 + tc4] = o;
  }
}

// ---------------- edge-GEMM v9: direct meta reads (no srcl/awl LDS), 2 barriers ----------------
__global__ __launch_bounds__(512, 1) void k_edge9(
    const u16* __restrict__ xb, const u16* __restrict__ wt,   // wt: layer base [R][HK][D]
    const int* __restrict__ indptrR, const int* __restrict__ padBase,
    const int* __restrict__ srcR, const float* __restrict__ aw,
    u16* __restrict__ m) {
  __shared__ u16 atile[128 * 128];     // 32 KB, XOR-swizzled
  __shared__ u16 outb[128 * 128];      // 32 KB, epilogue staging
  const int t = threadIdx.x;
  const int b128 = blockIdx.x * 128;
  if (b128 >= padBase[R_]) return;     // block-uniform tail guard
  int r = 0;
  while (b128 >= padBase[r + 1]) ++r;  // block-uniform, <=8 iters
  const int ip0 = indptrR[r * N_];
  const int cnt = indptrR[(r + 1) * N_] - ip0;
  const int local0 = b128 - padBase[r];
  const u16* wrp = wt + (size_t)r * HK_ * D_;
  const int wid = t >> 6, lane = t & 63;
  const int l15 = lane & 15, l4 = lane >> 4;
  // B-frags issued FIRST (L2-hot; latency overlaps A-gather)
  short8 breg[4][4];                   // [ks][h]
#pragma unroll
  for (int ks = 0; ks < 4; ++ks)
#pragma unroll
    for (int h = 0; h < 4; ++h) {
      int c = (wid + 8 * h) * 16 + l15;
      breg[ks][h] = *(const short8*)(wrp + (size_t)c * 128 + ks * 32 + l4 * 8);
    }
  // A gather -> LDS; src index read directly (16 consecutive threads share one
  // srcR address -> broadcast). No meta barrier.
#pragma unroll
  for (int p = 0; p < 4; ++p) {
    int idx = t + p * 512;
    int row = idx >> 4, seg = idx & 15;
    int lidx = local0 + row;
    int s = (lidx < cnt) ? srcR[ip0 + lidx] : 0;
    uint4 v = *(const uint4*)(xb + (size_t)s * 128 + seg * 8);
    *(uint4*)((char*)atile + row * 256 + ((seg * 16) ^ ((row & 7) << 4))) = v;
  }
  // per-lane aw for epilogue rows (independent of MFMA; overlaps it)
  float4 awreg[8];
#pragma unroll
  for (int i = 0; i < 8; ++i) {
    int row = i * 16 + l15;
    int lidx = local0 + row;
    awreg[i] = (lidx < cnt) ? *(const float4*)(aw + (size_t)(ip0 + lidx) * 4)
                            : make_float4(0.f, 0.f, 0.f, 0.f);
  }
  __syncthreads();   // A visible
  // MFMA: 128 rows x 16 out-cols (4 orig colfrags) x K=128 -> 128 MFMA/wave
  f32x4 acc[8][4];                     // [row i][h]
#pragma unroll
  for (int i = 0; i < 8; ++i)
#pragma unroll
    for (int h = 0; h < 4; ++h) acc[i][h] = (f32x4){0.f, 0.f, 0.f, 0.f};
#pragma unroll
  for (int ks = 0; ks < 4; ++ks) {
    short8 av[8];
#pragma unroll
    for (int i = 0; i < 8; ++i) {
      int row = i * 16 + l15;
      av[i] = *(const short8*)((char*)atile + row * 256 +
                ((l4 * 16 + ks * 64) ^ ((row & 7) << 4)));
    }
#pragma unroll
    for (int i = 0; i < 8; ++i)
#pragma unroll
      for (int h = 0; h < 4; ++h)
        // swapped operands: lane holds row = i*16+l15, cols (wid+8h)*16 + l4*4 + rg
        acc[i][h] = __builtin_amdgcn_mfma_f32_16x16x32_bf16(breg[ks][h], av[i],
                                                            acc[i][h], 0, 0, 0);
  }
  // epilogue phase A: head-reduce -> outb (separate region: no pre-barrier needed)
#pragma unroll
  for (int i = 0; i < 8; ++i) {
    int row = i * 16 + l15;
    const float4 awf = awreg[i];
    float v0 = awf.x * acc[i][0][0] + awf.y * acc[i][1][0] + awf.z * acc[i][2][0] + awf.w * acc[i][3][0];
    float v1 = awf.x * acc[i][0][1] + awf.y * acc[i][1][1] + awf.z * acc[i][2][1] + awf.w * acc[i][3][1];
    float v2 = awf.x * acc[i][0][2] + awf.y * acc[i][1][2] + awf.z * acc[i][2][2] + awf.w * acc[i][3][2];
    float v3 = awf.x * acc[i][0][3] + awf.y * acc[i][1][3] + awf.z * acc[i][2][3] + awf.w * acc[i][3][3];
    uint2 o;
    o.x = (u32)bfr(v0) | ((u32)bfr(v1) << 16);
    o.y = (u32)bfr(v2) | ((u32)bfr(v3) << 16);
    *(uint2*)((char*)outb + row * 256 + ((wid * 32 + l4 * 8) ^ ((row & 7) << 4))) = o;
  }
  __syncthreads();   // outb complete across waves
  // phase B: coalesced full-line stores (64B per thread)
  {
    int row = t >> 2, c0 = (t & 3) * 64;   // byte offsets within 256B row
    char* gout = (char*)(m + (size_t)(b128 + row) * 128) + c0;
#pragma unroll
    for (int qq = 0; qq < 4; ++qq) {
      uint4 v = *(const uint4*)((char*)outb + row * 256 + ((c0 + qq * 16) ^ ((row & 7) << 4)));
      *(uint4*)(gout + qq * 16) = v;
    }
  }
}

// ---------------- fused: aggregate + bias/relu + x/xb + next-layer q,k ----------------
__global__ __launch_bounds__(256) void k_aggqk(
    const int* __restrict__ indptrR, const int* __restrict__ padBase,
    const u16* __restrict__ m, const float* __restrict__ Bl,
    const float* __restrict__ WQK, int doqk,
    float* __restrict__ xout, u16* __restrict__ xbout,
    float* __restrict__ q, float* __restrict__ kk) {
  __shared__ float wqs[128 * 64];      // 32 KB
  __shared__ float xrow[4][128];
  const int t = threadIdx.x;
  if (doqk) {
#pragma unroll
    for (int p = 0; p < 8; ++p)
      *(float4*)&wqs[(t + p * 256) * 4] = *(const float4*)&WQK[(t + p * 256) * 4];
  }
  const int w = t >> 6;
  int n = blockIdx.x * 4 + w;
  int lane = t & 63;
  float s0 = 0.f, s1 = 0.f;   // d = 2*lane, 2*lane+1
#pragma unroll
  for (int r = 0; r < R_; ++r) {
    int ip0 = indptrR[r * N_];
    int j0 = indptrR[r * N_ + n], j1 = indptrR[r * N_ + n + 1];
    int base = padBase[r] + (j0 - ip0);
    int cntn = j1 - j0;
    int j = 0;
    for (; j + 1 < cntn; j += 2) {      // 2-wide for load ILP
      u32 v0 = *((const u32*)(m + (size_t)(base + j) * 128) + lane);
      u32 v1 = *((const u32*)(m + (size_t)(base + j + 1) * 128) + lane);
      s0 += bf2f(v0 & 0xffffu) + bf2f(v1 & 0xffffu);
      s1 += bf2f(v0 >> 16) + bf2f(v1 >> 16);
    }
    if (j < cntn) {
      u32 v0 = *((const u32*)(m + (size_t)(base + j) * 128) + lane);
      s0 += bf2f(v0 & 0xffffu);
      s1 += bf2f(v0 >> 16);
    }
  }
  float2 o;
  o.x = fmaxf(s0 + Bl[2 * lane], 0.f);
  o.y = fmaxf(s1 + Bl[2 * lane + 1], 0.f);
  *((float2*)(xout + (size_t)n * D_) + lane) = o;
  ((u32*)(xbout + (size_t)n * D_))[lane] = (u32)bfr(o.x) | ((u32)bfr(o.y) << 16);
  if (doqk) {
    xrow[w][2 * lane] = o.x;
    xrow[w][2 * lane + 1] = o.y;
    __syncthreads();   // wqs + xrow visible (doqk is uniform kernel arg)
    const float* xr = xrow[w];
    float s = 0.f;
#pragma unroll
    for (int d4 = 0; d4 < 32; ++d4) {
      const float4 xv = *(const float4*)&xr[d4 * 4];
      s += xv.x * wqs[(d4 * 4 + 0) * 64 + lane] + xv.y * wqs[(d4 * 4 + 1) * 64 + lane] +
           xv.z * wqs[(d4 * 4 + 2) * 64 + lane] + xv.w * wqs[(d4 * 4 + 3) * 64 + lane];
    }
    if (lane < 32) q[(size_t)n * 32 + lane] = s;
    else           kk[(size_t)n * 32 + (lane - 32)] = s;
  }
}

// ---------------- graph mean-pool ----------------
__global__ void k_pool(const float* __restrict__ x, float* __restrict__ pooled) {
  int i = blockIdx.x * blockDim.x + threadIdx.x; // G*D
  if (i >= G_ * D_) return;
  int d = i & 127, g = i >> 7;
  float s = 0.f;
  for (int j = 0; j < NPG_; ++j) s += x[(size_t)(g * NPG_ + j) * D_ + d];
  pooled[i] = s * (1.0f / NPG_);
}

// ---------------- head MLP ----------------
__global__ void k_head(const float* __restrict__ pooled, const float* __restrict__ fc1w,
                       const float* __restrict__ fc1b, const float* __restrict__ polw,
                       const float* __restrict__ polb, const float* __restrict__ valw,
                       const float* __restrict__ valb, float* __restrict__ out) {
  int g = blockIdx.x;
  int t = threadIdx.x; // 64
  __shared__ float hb[64];
  const float* p = pooled + (size_t)g * D_;
  float s = fc1b[t];
  for (int d = 0; d < D_; ++d) s += p[d] * fc1w[d * 64 + t];
  hb[t] = fmaxf(s, 0.f);
  __syncthreads();
  if (t < 7) {
    float s2 = polb[t];
    for (int j = 0; j < 64; ++j) s2 += hb[j] * polw[j * 7 + t];
    out[g * 7 + t] = s2;
  } else if (t == 7) {
    float s2 = valb[0];
    for (int j = 0; j < 64; ++j) s2 += hb[j] * valw[j];
    out[G_ * 7 + g] = tanhf(s2);
  }
}

extern "C" void kernel_launch(void* const* d_in, const int* in_sizes, int n_in,
                              void* d_out, int out_size, void* d_ws, size_t ws_size,
                              hipStream_t stream) {
  (void)in_sizes; (void)n_in; (void)out_size;
  const int*   x_nodes = (const int*)d_in[0];
  const int*   eidx    = (const int*)d_in[1];
  const int*   etype   = (const int*)d_in[2];
  const float* emb     = (const float*)d_in[4];
  const float* W       = (const float*)d_in[5];
  const float* Q       = (const float*)d_in[6];
  const float* Km      = (const float*)d_in[7];
  const float* B       = (const float*)d_in[8];
  const float* fc1w    = (const float*)d_in[9];
  const float* fc1b    = (const float*)d_in[10];
  const float* polw    = (const float*)d_in[11];
  const float* polb    = (const float*)d_in[12];
  const float* valw    = (const float*)d_in[13];
  const float* valb    = (const float*)d_in[14];
  float* out = (float*)d_out;
  const int* srcA = eidx;        // edge_index[0,:]
  const int* dstA = eidx + E_;   // edge_index[1,:]

  char* p = (char*)d_ws;
  size_t used = 0;
  auto carve = [&](size_t bytes) {
    char* q = p;
    size_t adv = (bytes + 255) & ~(size_t)255;
    p += adv;
    used += adv;
    return q;
  };
  float* x_cur  = (float*)carve((size_t)N_ * D_ * 4);            // 10.5 MB
  float* x_nxt  = (float*)carve((size_t)N_ * D_ * 4);            // 10.5 MB
  u16*   xbf    = (u16*)carve((size_t)N_ * D_ * 2);              // 5.2 MB
  u16*   mbuf   = (u16*)carve((size_t)(E_ + R_ * 128) * D_ * 2); // 42.2 MB
  float* qbuf   = (float*)carve((size_t)N_ * 32 * 4);            // 2.6 MB
  float* kbuf   = (float*)carve((size_t)N_ * 32 * 4);            // 2.6 MB
  float* awbuf  = (float*)carve((size_t)E_ * H_ * 4);            // 2.6 MB
  float* WQKb   = (float*)carve((size_t)L_ * D_ * 64 * 4);       // 131 KB
  u16*   Wtb    = (u16*)carve((size_t)L_ * R_ * HK_ * D_ * 2);   // 4.2 MB
  float* pooled = (float*)carve((size_t)G_ * D_ * 4);
  int* countsR  = (int*)carve((size_t)R_ * N_ * 4);
  int* cursorR  = (int*)carve((size_t)R_ * N_ * 4);
  int* indptrR  = (int*)carve((size_t)(R_ * N_ + 1) * 4);
  int* slotOf   = (int*)carve((size_t)E_ * 4);
  int* srcR     = (int*)carve((size_t)E_ * 4);
  int* countsN  = (int*)carve((size_t)N_ * 4);
  int* cursorN  = (int*)carve((size_t)N_ * 4);
  int* indptrN  = (int*)carve((size_t)(N_ + 1) * 4);
  int* esortD   = (int*)carve((size_t)E_ * 4);
  int* padBase  = (int*)carve((size_t)(R_ + 1) * 4);
  int* bsumR    = (int*)carve((size_t)160 * 4);
  int* bsumN    = (int*)carve((size_t)32 * 4);
  if (used > ws_size) return;  // defensive: fail via poisoned output, not OOB crash

  constexpr int RN = R_ * N_;          // 163840
  constexpr int EDGE_BLOCKS = E_ / 128 + R_;  // 1288 (covers padding)

  // ---- fused CSR builds + one-time precomputes ----
  k_zero2<<<(RN + N_ + 255) / 256, 256, 0, stream>>>(countsR, countsN);
  k_count_both<<<E_ / 256, 256, 0, stream>>>(dstA, etype, countsR, countsN);
  k_bsum2<<<180, 256, 0, stream>>>(countsR, countsN, bsumR, bsumN);
  k_bscan2<<<1, 256, 0, stream>>>(bsumR, bsumN, indptrR + RN, indptrN + N_, padBase);
  k_scan32<<<180, 256, 0, stream>>>(countsR, countsN, bsumR, bsumN,
                                    indptrR, cursorR, indptrN, cursorN);
  k_scatter_both<<<E_ / 256, 256, 0, stream>>>(dstA, etype, srcA, cursorR, cursorN,
                                               slotOf, srcR, esortD);
  k_wqk_all<<<(L_ * R_ * D_ * 64) / 256, 256, 0, stream>>>(W, Q, Km, WQKb);
  k_cvt_w_all<<<dim3(HK_ / 64, D_ / 64, L_ * R_), 256, 0, stream>>>(W, Wtb);
  k_embed_qk<<<N_ / 32, 256, 0, stream>>>(x_nodes, emb, WQKb, x_cur, xbf, qbuf, kbuf);

  for (int l = 0; l < L_; ++l) {
    const float* Bl = B + (size_t)l * D_;
    k_attn<<<N_ / 4, 256, 0, stream>>>(indptrN, esortD, srcA, etype, qbuf, kbuf,
                                       slotOf, awbuf);
    k_edge9<<<EDGE_BLOCKS, 512, 0, stream>>>(xbf, Wtb + (size_t)l * R_ * HK_ * D_,
                                             indptrR, padBase, srcR, awbuf, mbuf);
    int doqk = (l < L_ - 1) ? 1 : 0;
    k_aggqk<<<N_ / 4, 256, 0, stream>>>(indptrR, padBase, mbuf, Bl,
                                        WQKb + (size_t)(l + 1) * D_ * 64 * (doqk ? 1 : 0),
                                        doqk, x_nxt, xbf, qbuf, kbuf);
    float* tmp = x_cur; x_cur = x_nxt; x_nxt = tmp;
  }

  k_pool<<<(G_ * D_) / 256, 256, 0, stream>>>(x_cur, pooled);
  k_head<<<G_, 64, 0, stream>>>(pooled, fc1w, fc1b, polw, polb, valw, valb, out);
}

// Round 18
// 502.292 us; speedup vs baseline: 1.2066x; 1.2066x over previous
//
#include <hip/hip_runtime.h>
#include <cstdint>
#include <cstddef>

constexpr int N_  = 20480;
constexpr int E_  = 163840;
constexpr int G_  = 512;
constexpr int D_  = 128;
constexpr int H_  = 4;
constexpr int R_  = 8;
constexpr int L_  = 4;
constexpr int HK_ = 512;   // H*D
constexpr int NPG_ = N_ / G_; // 40

typedef short short8 __attribute__((ext_vector_type(8)));
typedef float f32x4 __attribute__((ext_vector_type(4)));
typedef unsigned short u16;
typedef unsigned int u32;

__device__ inline u16 bfr(float f) {  // fp32 -> bf16 RNE
  u32 u = __builtin_bit_cast(u32, f);
  return (u16)((u + 0x7fffu + ((u >> 16) & 1u)) >> 16);
}
__device__ inline float bf2f(u32 lo16) { return __builtin_bit_cast(float, lo16 << 16); }
__device__ inline float lrelu(float v) { return v >= 0.f ? v : 0.2f * v; }

// ---------------- fused zero: countsR (RN) + countsN (N) ----------------
__global__ void k_zero2(int* __restrict__ cR, int* __restrict__ cN) {
  int i = blockIdx.x * blockDim.x + threadIdx.x;
  if (i < R_ * N_) cR[i] = 0;
  else if (i < R_ * N_ + N_) cN[i - R_ * N_] = 0;
}

// ---------------- fused count: rel-CSR + dst-CSR ----------------
__global__ void k_count_both(const int* __restrict__ dst, const int* __restrict__ et,
                             int* __restrict__ cR, int* __restrict__ cN) {
  int e = blockIdx.x * blockDim.x + threadIdx.x;
  if (e < E_) {
    int d = dst[e];
    atomicAdd(&cR[et[e] * N_ + d], 1);
    atomicAdd(&cN[d], 1);
  }
}

// ---------------- fused per-block sums ----------------
__global__ void k_bsum2(const int* __restrict__ cR, const int* __restrict__ cN,
                        int* __restrict__ bsumR, int* __restrict__ bsumN) {
  int b = blockIdx.x;
  const int* src = (b < 160) ? &cR[b * 1024] : &cN[(b - 160) * 1024];
  int t = threadIdx.x;
  const int4 v = *(const int4*)&src[t * 4];
  int s = v.x + v.y + v.z + v.w;
#pragma unroll
  for (int o = 32; o; o >>= 1) s += __shfl_down(s, o, 64);
  __shared__ int ws_[4];
  if ((t & 63) == 0) ws_[t >> 6] = s;
  __syncthreads();
  if (t == 0) {
    int tot = ws_[0] + ws_[1] + ws_[2] + ws_[3];
    if (b < 160) bsumR[b] = tot; else bsumN[b - 160] = tot;
  }
}

// ---------------- fused block-sum scan + totals + padBase (r6 lesson: totals MUST be written) ----------------
__global__ void k_bscan2(int* __restrict__ bsumR, int* __restrict__ bsumN,
                         int* __restrict__ totR, int* __restrict__ totN,
                         int* __restrict__ padBase) {
  __shared__ int shR[160];
  __shared__ int shN[20];
  int t = threadIdx.x;
  if (t < 160) shR[t] = bsumR[t];
  if (t < 20) shN[t] = bsumN[t];
  __syncthreads();
  if (t == 0) {
    int run = 0;
    for (int i = 0; i < 160; ++i) { int v = shR[i]; shR[i] = run; run += v; }
    totR[0] = run;   // = E
    int cum = 0;
    for (int r = 0; r < R_; ++r) {          // padBase from relation boundaries (block r*20)
      padBase[r] = cum;
      int lo = shR[r * 20];
      int hi = (r == R_ - 1) ? run : shR[(r + 1) * 20];
      cum += (hi - lo + 127) & ~127;
    }
    padBase[R_] = cum;
    int run2 = 0;
    for (int i = 0; i < 20; ++i) { int v = shN[i]; shN[i] = run2; run2 += v; }
    totN[0] = run2;  // = E
  }
  __syncthreads();
  if (t < 160) bsumR[t] = shR[t];
  if (t < 20) bsumN[t] = shN[t];
}

// ---------------- fused full scan write ----------------
__global__ void k_scan32(const int* __restrict__ cR, const int* __restrict__ cN,
                         const int* __restrict__ bsumR, const int* __restrict__ bsumN,
                         int* __restrict__ ipR, int* __restrict__ curR,
                         int* __restrict__ ipN, int* __restrict__ curN) {
  __shared__ int ts[256];
  int b = blockIdx.x;
  const int* c;
  int off0;
  int* indptr;
  int* cursor;
  int lb;
  if (b < 160) { c = cR; off0 = bsumR[b]; indptr = ipR; cursor = curR; lb = b; }
  else { c = cN; off0 = bsumN[b - 160]; indptr = ipN; cursor = curN; lb = b - 160; }
  int t = threadIdx.x;
  int base = lb * 1024 + t * 4;
  const int4 v = *(const int4*)&c[base];
  int s0 = v.x, s01 = v.x + v.y, s012 = s01 + v.z, s = s012 + v.w;
  ts[t] = s;
  __syncthreads();
#pragma unroll
  for (int o = 1; o < 256; o <<= 1) {
    int add = (t >= o) ? ts[t - o] : 0;
    __syncthreads();
    ts[t] += add;
    __syncthreads();
  }
  int off = off0 + (t ? ts[t - 1] : 0);
  int4 o4 = make_int4(off, off + s0, off + s01, off + s012);
  *(int4*)&indptr[base] = o4;
  *(int4*)&cursor[base] = o4;
}

// ---------------- fused scatter: rel slots (slotOf,srcR) + dst-CSR (esortD) ----------------
__global__ void k_scatter_both(const int* __restrict__ dst, const int* __restrict__ et,
                               const int* __restrict__ src, int* __restrict__ curR,
                               int* __restrict__ curN, int* __restrict__ slotOf,
                               int* __restrict__ srcR, int* __restrict__ esortD) {
  int e = blockIdx.x * blockDim.x + threadIdx.x;
  if (e < E_) {
    int d = dst[e];
    int p = atomicAdd(&curR[et[e] * N_ + d], 1);
    slotOf[e] = p;
    srcR[p] = src[e];
    int p2 = atomicAdd(&curN[d], 1);
    esortD[p2] = e;
  }
}

// ---------------- WQK for ALL layers: wave per (l,r,d) row ----------------
__global__ __launch_bounds__(256) void k_wqk_all(const float* __restrict__ W,
                                                 const float* __restrict__ Q,
                                                 const float* __restrict__ Km,
                                                 float* __restrict__ WQK) {
  int gw = (blockIdx.x * 256 + threadIdx.x) >> 6;  // 0..L*R*D-1 = 4095
  int lane = threadIdx.x & 63;
  int d = gw & 127, r = (gw >> 7) & 7, l = gw >> 10;
  const float* wrow = W + (((size_t)l * R_ + r) * D_ + d) * HK_;
  const float* Ql = Q + (size_t)l * HK_ * H_;
  const float* Kl = Km + (size_t)l * HK_ * H_;
  float acc[8] = {0.f, 0.f, 0.f, 0.f, 0.f, 0.f, 0.f, 0.f};
#pragma unroll
  for (int it = 0; it < 8; ++it) {
    int k = it * 64 + lane;
    float w = wrow[k];
    const float4 qv = *(const float4*)&Ql[k * 4];
    const float4 kv = *(const float4*)&Kl[k * 4];
    acc[0] += w * qv.x; acc[1] += w * qv.y; acc[2] += w * qv.z; acc[3] += w * qv.w;
    acc[4] += w * kv.x; acc[5] += w * kv.y; acc[6] += w * kv.z; acc[7] += w * kv.w;
  }
#pragma unroll
  for (int o = 32; o; o >>= 1)
#pragma unroll
    for (int j = 0; j < 8; ++j) acc[j] += __shfl_down(acc[j], o, 64);
  if (lane == 0) {
#pragma unroll
    for (int h = 0; h < 4; ++h) {
      WQK[((size_t)l * D_ + d) * 64 + r * 4 + h] = acc[h];
      WQK[((size_t)l * D_ + d) * 64 + 32 + r * 4 + h] = acc[4 + h];
    }
  }
}

// ---------------- fused embed + layer-0 q,k (32 nodes/block) ----------------
__global__ __launch_bounds__(256) void k_embed_qk(
    const int* __restrict__ xn, const float* __restrict__ emb,
    const float* __restrict__ WQK, float* __restrict__ x, u16* __restrict__ xb,
    float* __restrict__ q, float* __restrict__ kk) {
  __shared__ float xs[32][129];
  __shared__ float wq[128][64];
  __shared__ int xnl[32];
  const int t = threadIdx.x;
  const int n0 = blockIdx.x * 32;
  if (t < 32) xnl[t] = xn[n0 + t];
#pragma unroll
  for (int p = 0; p < 8; ++p) {
    int idx = t + p * 256;
    int row = idx >> 4, c4 = (idx & 15) * 4;
    *(float4*)&wq[row][c4] = *(const float4*)&WQK[row * 64 + c4];
  }
  __syncthreads();
#pragma unroll
  for (int p = 0; p < 16; ++p) {      // 4096 elems of x
    int idx = t + p * 256;
    int node = idx >> 7, d = idx & 127;
    float v = emb[xnl[node] * D_ + d];
    xs[node][d] = v;
    x[(size_t)(n0 + node) * D_ + d] = v;
    xb[(size_t)(n0 + node) * D_ + d] = bfr(v);
  }
  __syncthreads();
  const int node = t >> 3, cq = t & 7;
  float s[8];
#pragma unroll
  for (int j = 0; j < 8; ++j) s[j] = 0.f;
  for (int k = 0; k < 128; ++k) {
    float xv = xs[node][k];
#pragma unroll
    for (int j = 0; j < 8; ++j) s[j] = fmaf(xv, wq[k][cq * 8 + j], s[j]);
  }
#pragma unroll
  for (int j = 0; j < 8; ++j) {
    int c = cq * 8 + j;
    if (c < 32) q[(size_t)(n0 + node) * 32 + c] = s[j];
    else        kk[(size_t)(n0 + node) * 32 + (c - 32)] = s[j];
  }
}

// ---------------- fused attention softmax: wave per dst node, normalized aw out ----------------
__global__ __launch_bounds__(256) void k_attn(
    const int* __restrict__ ipN, const int* __restrict__ esD,
    const int* __restrict__ src, const int* __restrict__ et,
    const float* __restrict__ q, const float* __restrict__ kk,
    const int* __restrict__ slotOf, float* __restrict__ aw) {
  int n = blockIdx.x * 4 + (threadIdx.x >> 6);
  int lane = threadIdx.x & 63;
  int j0 = ipN[n], j1 = ipN[n + 1];
  int deg = j1 - j0;
  if (deg == 0) return;            // wave-uniform
  int h = lane & 3;
  if (deg <= 16) {                 // fast path (covers most nodes)
    int ei = lane >> 2;
    float a = -3.4e38f;
    int slot = 0;
    if (ei < deg) {
      int e = esD[j0 + ei];
      int r = et[e];
      slot = slotOf[e];
      a = lrelu(q[(size_t)n * 32 + r * 4 + h] + kk[(size_t)src[e] * 32 + r * 4 + h]);
    }
    float m = a;
#pragma unroll
    for (int o = 4; o < 64; o <<= 1) m = fmaxf(m, __shfl_xor(m, o, 64));
    float ex = (ei < deg) ? expf(a - m) : 0.f;
    float s = ex;
#pragma unroll
    for (int o = 4; o < 64; o <<= 1) s += __shfl_xor(s, o, 64);
    if (ei < deg) aw[(size_t)slot * 4 + h] = ex * (0.25f / (s + 1e-16f));
    return;
  }
  // general path (rare)
  int nch = (deg + 15) >> 4;
  float m = -3.4e38f;
  for (int c = 0; c < nch; ++c) {
    int ei = c * 16 + (lane >> 2);
    if (ei < deg) {
      int e = esD[j0 + ei];
      int r = et[e];
      float a = lrelu(q[(size_t)n * 32 + r * 4 + h] + kk[(size_t)src[e] * 32 + r * 4 + h]);
      m = fmaxf(m, a);
    }
  }
#pragma unroll
  for (int o = 4; o < 64; o <<= 1) m = fmaxf(m, __shfl_xor(m, o, 64));
  float s = 0.f;
  for (int c = 0; c < nch; ++c) {
    int ei = c * 16 + (lane >> 2);
    if (ei < deg) {
      int e = esD[j0 + ei];
      int r = et[e];
      float a = lrelu(q[(size_t)n * 32 + r * 4 + h] + kk[(size_t)src[e] * 32 + r * 4 + h]);
      float ex = expf(a - m);
      s += ex;
      aw[(size_t)slotOf[e] * 4 + h] = ex;
    }
  }
#pragma unroll
  for (int o = 4; o < 64; o <<= 1) s += __shfl_xor(s, o, 64);
  float inv = 0.25f / (s + 1e-16f);
  for (int c = 0; c < nch; ++c) {
    int ei = c * 16 + (lane >> 2);
    if (ei < deg) {
      int e = esD[j0 + ei];
      aw[(size_t)slotOf[e] * 4 + h] *= inv;
    }
  }
}

// W fp32 [L][R][D][HK] -> wt bf16 [L][R][HK][D]  (all layers, z = l*R+r)
__global__ void k_cvt_w_all(const float* __restrict__ W, u16* __restrict__ wt) {
  __shared__ u16 tile[64][65];
  const int z = blockIdx.z, k0 = blockIdx.y * 64, c0 = blockIdx.x * 64;
  const int t = threadIdx.x;
  const int tk = t >> 4, tc4 = (t & 15) * 4;
  const float* Wz = W + (size_t)z * D_ * HK_;
  u16* wz = wt + (size_t)z * HK_ * D_;
#pragma unroll
  for (int p = 0; p < 4; ++p) {
    int krow = tk + p * 16;
    const float4 v = *(const float4*)&Wz[(size_t)(k0 + krow) * HK_ + c0 + tc4];
    tile[tc4 + 0][krow] = bfr(v.x);
    tile[tc4 + 1][krow] = bfr(v.y);
    tile[tc4 + 2][krow] = bfr(v.z);
    tile[tc4 + 3][krow] = bfr(v.w);
  }
  __syncthreads();
#pragma unroll
  for (int p = 0; p < 4; ++p) {
    int crow = tk + p * 16;
    uint2 o;
    o.x = (u32)tile[crow][tc4 + 0] | ((u32)tile[crow][tc4 + 1] << 16);
    o.y = (u32)tile[crow][tc4 + 2] | ((u32)tile[crow][tc4 + 3] << 16);
    *(uint2*)&wz[(size_t)(c0 + crow) * D_ + k0 + tc4] = o;
  }
}

// ---------------- edge-GEMM v8: 128-edge one-shot tiles; separate out-LDS (3 barriers) ----------------
// Proven-best config (r15, 502 us). NT stores (r14), direct-meta (r17), node-fusion
// (r16), persistent B (r9-r12) all regressed -- keep exactly this structure.
__global__ __launch_bounds__(512, 1) void k_edge8(
    const u16* __restrict__ xb, const u16* __restrict__ wt,   // wt: layer base [R][HK][D]
    const int* __restrict__ indptrR, const int* __restrict__ padBase,
    const int* __restrict__ srcR, const float* __restrict__ aw,
    u16* __restrict__ m) {
  __shared__ u16 atile[128 * 128];     // 32 KB, XOR-swizzled
  __shared__ u16 outb[128 * 128];      // 32 KB, epilogue staging (no post-MFMA barrier)
  __shared__ float awl[128][4];
  __shared__ int srcl[128];
  const int t = threadIdx.x;
  const int b128 = blockIdx.x * 128;
  if (b128 >= padBase[R_]) return;     // block-uniform tail guard
  int r = 0;
  while (b128 >= padBase[r + 1]) ++r;  // block-uniform, <=8 iters
  const int ip0 = indptrR[r * N_];
  const int cnt = indptrR[(r + 1) * N_] - ip0;
  const int local0 = b128 - padBase[r];
  const u16* wrp = wt + (size_t)r * HK_ * D_;
  const int wid = t >> 6, lane = t & 63;
  const int l15 = lane & 15, l4 = lane >> 4;
  // B-frags issued FIRST (L2-hot; latency overlaps meta + A-gather)
  short8 breg[4][4];                   // [ks][h]
#pragma unroll
  for (int ks = 0; ks < 4; ++ks)
#pragma unroll
    for (int h = 0; h < 4; ++h) {
      int c = (wid + 8 * h) * 16 + l15;
      breg[ks][h] = *(const short8*)(wrp + (size_t)c * 128 + ks * 32 + l4 * 8);
    }
  // meta (rel-sorted slots: coalesced)
  if (t < 128) {
    int lidx = local0 + t;
    if (lidx < cnt) {
      srcl[t] = srcR[ip0 + lidx];
      *(float4*)awl[t] = *(const float4*)(aw + (size_t)(ip0 + lidx) * 4);
    } else {
      srcl[t] = 0;
      *(float4*)awl[t] = make_float4(0.f, 0.f, 0.f, 0.f);
    }
  }
  __syncthreads();   // meta visible
  // A gather -> LDS (4 uint4/thread; 16 lanes per row)
#pragma unroll
  for (int p = 0; p < 4; ++p) {
    int idx = t + p * 512;
    int row = idx >> 4, seg = idx & 15;
    uint4 v = *(const uint4*)(xb + (size_t)srcl[row] * 128 + seg * 8);
    *(uint4*)((char*)atile + row * 256 + ((seg * 16) ^ ((row & 7) << 4))) = v;
  }
  __syncthreads();   // A visible
  // MFMA: 128 rows x 16 out-cols (4 orig colfrags) x K=128 -> 128 MFMA/wave
  f32x4 acc[8][4];                     // [row i][h]
#pragma unroll
  for (int i = 0; i < 8; ++i)
#pragma unroll
    for (int h = 0; h < 4; ++h) acc[i][h] = (f32x4){0.f, 0.f, 0.f, 0.f};
#pragma unroll
  for (int ks = 0; ks < 4; ++ks) {
    short8 av[8];
#pragma unroll
    for (int i = 0; i < 8; ++i) {
      int row = i * 16 + l15;
      av[i] = *(const short8*)((char*)atile + row * 256 +
                ((l4 * 16 + ks * 64) ^ ((row & 7) << 4)));
    }
#pragma unroll
    for (int i = 0; i < 8; ++i)
#pragma unroll
      for (int h = 0; h < 4; ++h)
        // swapped operands: lane holds row = i*16+l15, cols (wid+8h)*16 + l4*4 + rg
        acc[i][h] = __builtin_amdgcn_mfma_f32_16x16x32_bf16(breg[ks][h], av[i],
                                                            acc[i][h], 0, 0, 0);
  }
  // epilogue phase A: head-reduce -> outb (separate region: no barrier needed here)
#pragma unroll
  for (int i = 0; i < 8; ++i) {
    int row = i * 16 + l15;
    const float4 awf = *(const float4*)awl[row];
    float v0 = awf.x * acc[i][0][0] + awf.y * acc[i][1][0] + awf.z * acc[i][2][0] + awf.w * acc[i][3][0];
    float v1 = awf.x * acc[i][0][1] + awf.y * acc[i][1][1] + awf.z * acc[i][2][1] + awf.w * acc[i][3][1];
    float v2 = awf.x * acc[i][0][2] + awf.y * acc[i][1][2] + awf.z * acc[i][2][2] + awf.w * acc[i][3][2];
    float v3 = awf.x * acc[i][0][3] + awf.y * acc[i][1][3] + awf.z * acc[i][2][3] + awf.w * acc[i][3][3];
    uint2 o;
    o.x = (u32)bfr(v0) | ((u32)bfr(v1) << 16);
    o.y = (u32)bfr(v2) | ((u32)bfr(v3) << 16);
    *(uint2*)((char*)outb + row * 256 + ((wid * 32 + l4 * 8) ^ ((row & 7) << 4))) = o;
  }
  __syncthreads();   // outb complete across waves
  // phase B: coalesced full-line stores (64B per thread)
  {
    int row = t >> 2, c0 = (t & 3) * 64;   // byte offsets within 256B row
    char* gout = (char*)(m + (size_t)(b128 + row) * 128) + c0;
#pragma unroll
    for (int qq = 0; qq < 4; ++qq) {
      uint4 v = *(const uint4*)((char*)outb + row * 256 + ((c0 + qq * 16) ^ ((row & 7) << 4)));
      *(uint4*)(gout + qq * 16) = v;
    }
  }
}

// ---------------- fused: aggregate + bias/relu + x/xb + next-layer q,k ----------------
__global__ __launch_bounds__(256) void k_aggqk(
    const int* __restrict__ indptrR, const int* __restrict__ padBase,
    const u16* __restrict__ m, const float* __restrict__ Bl,
    const float* __restrict__ WQK, int doqk,
    float* __restrict__ xout, u16* __restrict__ xbout,
    float* __restrict__ q, float* __restrict__ kk) {
  __shared__ float wqs[128 * 64];      // 32 KB
  __shared__ float xrow[4][128];
  const int t = threadIdx.x;
  if (doqk) {
#pragma unroll
    for (int p = 0; p < 8; ++p)
      *(float4*)&wqs[(t + p * 256) * 4] = *(const float4*)&WQK[(t + p * 256) * 4];
  }
  const int w = t >> 6;
  int n = blockIdx.x * 4 + w;
  int lane = t & 63;
  float s0 = 0.f, s1 = 0.f;   // d = 2*lane, 2*lane+1
#pragma unroll
  for (int r = 0; r < R_; ++r) {
    int ip0 = indptrR[r * N_];
    int j0 = indptrR[r * N_ + n], j1 = indptrR[r * N_ + n + 1];
    int base = padBase[r] + (j0 - ip0);
    int cntn = j1 - j0;
    int j = 0;
    for (; j + 1 < cntn; j += 2) {      // 2-wide for load ILP
      u32 v0 = *((const u32*)(m + (size_t)(base + j) * 128) + lane);
      u32 v1 = *((const u32*)(m + (size_t)(base + j + 1) * 128) + lane);
      s0 += bf2f(v0 & 0xffffu) + bf2f(v1 & 0xffffu);
      s1 += bf2f(v0 >> 16) + bf2f(v1 >> 16);
    }
    if (j < cntn) {
      u32 v0 = *((const u32*)(m + (size_t)(base + j) * 128) + lane);
      s0 += bf2f(v0 & 0xffffu);
      s1 += bf2f(v0 >> 16);
    }
  }
  float2 o;
  o.x = fmaxf(s0 + Bl[2 * lane], 0.f);
  o.y = fmaxf(s1 + Bl[2 * lane + 1], 0.f);
  *((float2*)(xout + (size_t)n * D_) + lane) = o;
  ((u32*)(xbout + (size_t)n * D_))[lane] = (u32)bfr(o.x) | ((u32)bfr(o.y) << 16);
  if (doqk) {
    xrow[w][2 * lane] = o.x;
    xrow[w][2 * lane + 1] = o.y;
    __syncthreads();   // wqs + xrow visible (doqk is uniform kernel arg)
    const float* xr = xrow[w];
    float s = 0.f;
#pragma unroll
    for (int d4 = 0; d4 < 32; ++d4) {
      const float4 xv = *(const float4*)&xr[d4 * 4];
      s += xv.x * wqs[(d4 * 4 + 0) * 64 + lane] + xv.y * wqs[(d4 * 4 + 1) * 64 + lane] +
           xv.z * wqs[(d4 * 4 + 2) * 64 + lane] + xv.w * wqs[(d4 * 4 + 3) * 64 + lane];
    }
    if (lane < 32) q[(size_t)n * 32 + lane] = s;
    else           kk[(size_t)n * 32 + (lane - 32)] = s;
  }
}

// ---------------- graph mean-pool ----------------
__global__ void k_pool(const float* __restrict__ x, float* __restrict__ pooled) {
  int i = blockIdx.x * blockDim.x + threadIdx.x; // G*D
  if (i >= G_ * D_) return;
  int d = i & 127, g = i >> 7;
  float s = 0.f;
  for (int j = 0; j < NPG_; ++j) s += x[(size_t)(g * NPG_ + j) * D_ + d];
  pooled[i] = s * (1.0f / NPG_);
}

// ---------------- head MLP ----------------
__global__ void k_head(const float* __restrict__ pooled, const float* __restrict__ fc1w,
                       const float* __restrict__ fc1b, const float* __restrict__ polw,
                       const float* __restrict__ polb, const float* __restrict__ valw,
                       const float* __restrict__ valb, float* __restrict__ out) {
  int g = blockIdx.x;
  int t = threadIdx.x; // 64
  __shared__ float hb[64];
  const float* p = pooled + (size_t)g * D_;
  float s = fc1b[t];
  for (int d = 0; d < D_; ++d) s += p[d] * fc1w[d * 64 + t];
  hb[t] = fmaxf(s, 0.f);
  __syncthreads();
  if (t < 7) {
    float s2 = polb[t];
    for (int j = 0; j < 64; ++j) s2 += hb[j] * polw[j * 7 + t];
    out[g * 7 + t] = s2;
  } else if (t == 7) {
    float s2 = valb[0];
    for (int j = 0; j < 64; ++j) s2 += hb[j] * valw[j];
    out[G_ * 7 + g] = tanhf(s2);
  }
}

extern "C" void kernel_launch(void* const* d_in, const int* in_sizes, int n_in,
                              void* d_out, int out_size, void* d_ws, size_t ws_size,
                              hipStream_t stream) {
  (void)in_sizes; (void)n_in; (void)out_size;
  const int*   x_nodes = (const int*)d_in[0];
  const int*   eidx    = (const int*)d_in[1];
  const int*   etype   = (const int*)d_in[2];
  const float* emb     = (const float*)d_in[4];
  const float* W       = (const float*)d_in[5];
  const float* Q       = (const float*)d_in[6];
  const float* Km      = (const float*)d_in[7];
  const float* B       = (const float*)d_in[8];
  const float* fc1w    = (const float*)d_in[9];
  const float* fc1b    = (const float*)d_in[10];
  const float* polw    = (const float*)d_in[11];
  const float* polb    = (const float*)d_in[12];
  const float* valw    = (const float*)d_in[13];
  const float* valb    = (const float*)d_in[14];
  float* out = (float*)d_out;
  const int* srcA = eidx;        // edge_index[0,:]
  const int* dstA = eidx + E_;   // edge_index[1,:]

  char* p = (char*)d_ws;
  size_t used = 0;
  auto carve = [&](size_t bytes) {
    char* q = p;
    size_t adv = (bytes + 255) & ~(size_t)255;
    p += adv;
    used += adv;
    return q;
  };
  float* x_cur  = (float*)carve((size_t)N_ * D_ * 4);            // 10.5 MB
  float* x_nxt  = (float*)carve((size_t)N_ * D_ * 4);            // 10.5 MB
  u16*   xbf    = (u16*)carve((size_t)N_ * D_ * 2);              // 5.2 MB
  u16*   mbuf   = (u16*)carve((size_t)(E_ + R_ * 128) * D_ * 2); // 42.2 MB
  float* qbuf   = (float*)carve((size_t)N_ * 32 * 4);            // 2.6 MB
  float* kbuf   = (float*)carve((size_t)N_ * 32 * 4);            // 2.6 MB
  float* awbuf  = (float*)carve((size_t)E_ * H_ * 4);            // 2.6 MB
  float* WQKb   = (float*)carve((size_t)L_ * D_ * 64 * 4);       // 131 KB
  u16*   Wtb    = (u16*)carve((size_t)L_ * R_ * HK_ * D_ * 2);   // 4.2 MB
  float* pooled = (float*)carve((size_t)G_ * D_ * 4);
  int* countsR  = (int*)carve((size_t)R_ * N_ * 4);
  int* cursorR  = (int*)carve((size_t)R_ * N_ * 4);
  int* indptrR  = (int*)carve((size_t)(R_ * N_ + 1) * 4);
  int* slotOf   = (int*)carve((size_t)E_ * 4);
  int* srcR     = (int*)carve((size_t)E_ * 4);
  int* countsN  = (int*)carve((size_t)N_ * 4);
  int* cursorN  = (int*)carve((size_t)N_ * 4);
  int* indptrN  = (int*)carve((size_t)(N_ + 1) * 4);
  int* esortD   = (int*)carve((size_t)E_ * 4);
  int* padBase  = (int*)carve((size_t)(R_ + 1) * 4);
  int* bsumR    = (int*)carve((size_t)160 * 4);
  int* bsumN    = (int*)carve((size_t)32 * 4);
  if (used > ws_size) return;  // defensive: fail via poisoned output, not OOB crash

  constexpr int RN = R_ * N_;          // 163840
  constexpr int EDGE_BLOCKS = E_ / 128 + R_;  // 1288 (covers padding)

  // ---- fused CSR builds + one-time precomputes (9 setup dispatches) ----
  k_zero2<<<(RN + N_ + 255) / 256, 256, 0, stream>>>(countsR, countsN);
  k_count_both<<<E_ / 256, 256, 0, stream>>>(dstA, etype, countsR, countsN);
  k_bsum2<<<180, 256, 0, stream>>>(countsR, countsN, bsumR, bsumN);
  k_bscan2<<<1, 256, 0, stream>>>(bsumR, bsumN, indptrR + RN, indptrN + N_, padBase);
  k_scan32<<<180, 256, 0, stream>>>(countsR, countsN, bsumR, bsumN,
                                    indptrR, cursorR, indptrN, cursorN);
  k_scatter_both<<<E_ / 256, 256, 0, stream>>>(dstA, etype, srcA, cursorR, cursorN,
                                               slotOf, srcR, esortD);
  k_wqk_all<<<(L_ * R_ * D_ * 64) / 256, 256, 0, stream>>>(W, Q, Km, WQKb);
  k_cvt_w_all<<<dim3(HK_ / 64, D_ / 64, L_ * R_), 256, 0, stream>>>(W, Wtb);
  k_embed_qk<<<N_ / 32, 256, 0, stream>>>(x_nodes, emb, WQKb, x_cur, xbf, qbuf, kbuf);

  for (int l = 0; l < L_; ++l) {
    const float* Bl = B + (size_t)l * D_;
    k_attn<<<N_ / 4, 256, 0, stream>>>(indptrN, esortD, srcA, etype, qbuf, kbuf,
                                       slotOf, awbuf);
    k_edge8<<<EDGE_BLOCKS, 512, 0, stream>>>(xbf, Wtb + (size_t)l * R_ * HK_ * D_,
                                             indptrR, padBase, srcR, awbuf, mbuf);
    int doqk = (l < L_ - 1) ? 1 : 0;
    k_aggqk<<<N_ / 4, 256, 0, stream>>>(indptrR, padBase, mbuf, Bl,
                                        WQKb + (size_t)(l + 1) * D_ * 64 * (doqk ? 1 : 0),
                                        doqk, x_nxt, xbf, qbuf, kbuf);
    float* tmp = x_cur; x_cur = x_nxt; x_nxt = tmp;
  }

  k_pool<<<(G_ * D_) / 256, 256, 0, stream>>>(x_cur, pooled);
  k_head<<<G_, 64, 0, stream>>>(pooled, fc1w, fc1b, polw, polb, valw, valb, out);
}

// Round 19
// 454.244 us; speedup vs baseline: 1.3342x; 1.1058x over previous
//
#include <hip/hip_runtime.h>
#include <cstdint>
#include <cstddef>

constexpr int N_  = 20480;
constexpr int E_  = 163840;
constexpr int G_  = 512;
constexpr int D_  = 128;
constexpr int H_  = 4;
constexpr int R_  = 8;
constexpr int L_  = 4;
constexpr int HK_ = 512;   // H*D
constexpr int NPG_ = N_ / G_; // 40

typedef short short8 __attribute__((ext_vector_type(8)));
typedef float f32x4 __attribute__((ext_vector_type(4)));
typedef unsigned short u16;
typedef unsigned int u32;

__device__ inline u16 bfr(float f) {  // fp32 -> bf16 RNE
  u32 u = __builtin_bit_cast(u32, f);
  return (u16)((u + 0x7fffu + ((u >> 16) & 1u)) >> 16);
}
__device__ inline float bf2f(u32 lo16) { return __builtin_bit_cast(float, lo16 << 16); }
__device__ inline float lrelu(float v) { return v >= 0.f ? v : 0.2f * v; }

// ---------------- fused zero: countsR (RN) + countsN (N) ----------------
__global__ void k_zero2(int* __restrict__ cR, int* __restrict__ cN) {
  int i = blockIdx.x * blockDim.x + threadIdx.x;
  if (i < R_ * N_) cR[i] = 0;
  else if (i < R_ * N_ + N_) cN[i - R_ * N_] = 0;
}

// ---------------- fused count: rel-CSR + dst-CSR ----------------
__global__ void k_count_both(const int* __restrict__ dst, const int* __restrict__ et,
                             int* __restrict__ cR, int* __restrict__ cN) {
  int e = blockIdx.x * blockDim.x + threadIdx.x;
  if (e < E_) {
    int d = dst[e];
    atomicAdd(&cR[et[e] * N_ + d], 1);
    atomicAdd(&cN[d], 1);
  }
}

// ---------------- fused per-block sums ----------------
__global__ void k_bsum2(const int* __restrict__ cR, const int* __restrict__ cN,
                        int* __restrict__ bsumR, int* __restrict__ bsumN) {
  int b = blockIdx.x;
  const int* src = (b < 160) ? &cR[b * 1024] : &cN[(b - 160) * 1024];
  int t = threadIdx.x;
  const int4 v = *(const int4*)&src[t * 4];
  int s = v.x + v.y + v.z + v.w;
#pragma unroll
  for (int o = 32; o; o >>= 1) s += __shfl_down(s, o, 64);
  __shared__ int ws_[4];
  if ((t & 63) == 0) ws_[t >> 6] = s;
  __syncthreads();
  if (t == 0) {
    int tot = ws_[0] + ws_[1] + ws_[2] + ws_[3];
    if (b < 160) bsumR[b] = tot; else bsumN[b - 160] = tot;
  }
}

// ---------------- fused block-sum scan + totals + padBase (r6 lesson: totals MUST be written) ----------------
__global__ void k_bscan2(int* __restrict__ bsumR, int* __restrict__ bsumN,
                         int* __restrict__ totR, int* __restrict__ totN,
                         int* __restrict__ padBase) {
  __shared__ int shR[160];
  __shared__ int shN[20];
  int t = threadIdx.x;
  if (t < 160) shR[t] = bsumR[t];
  if (t < 20) shN[t] = bsumN[t];
  __syncthreads();
  if (t == 0) {
    int run = 0;
    for (int i = 0; i < 160; ++i) { int v = shR[i]; shR[i] = run; run += v; }
    totR[0] = run;   // = E
    int cum = 0;
    for (int r = 0; r < R_; ++r) {          // padBase from relation boundaries (block r*20)
      padBase[r] = cum;
      int lo = shR[r * 20];
      int hi = (r == R_ - 1) ? run : shR[(r + 1) * 20];
      cum += (hi - lo + 127) & ~127;
    }
    padBase[R_] = cum;
    int run2 = 0;
    for (int i = 0; i < 20; ++i) { int v = shN[i]; shN[i] = run2; run2 += v; }
    totN[0] = run2;  // = E
  }
  __syncthreads();
  if (t < 160) bsumR[t] = shR[t];
  if (t < 20) bsumN[t] = shN[t];
}

// ---------------- fused full scan write ----------------
__global__ void k_scan32(const int* __restrict__ cR, const int* __restrict__ cN,
                         const int* __restrict__ bsumR, const int* __restrict__ bsumN,
                         int* __restrict__ ipR, int* __restrict__ curR,
                         int* __restrict__ ipN, int* __restrict__ curN) {
  __shared__ int ts[256];
  int b = blockIdx.x;
  const int* c;
  int off0;
  int* indptr;
  int* cursor;
  int lb;
  if (b < 160) { c = cR; off0 = bsumR[b]; indptr = ipR; cursor = curR; lb = b; }
  else { c = cN; off0 = bsumN[b - 160]; indptr = ipN; cursor = curN; lb = b - 160; }
  int t = threadIdx.x;
  int base = lb * 1024 + t * 4;
  const int4 v = *(const int4*)&c[base];
  int s0 = v.x, s01 = v.x + v.y, s012 = s01 + v.z, s = s012 + v.w;
  ts[t] = s;
  __syncthreads();
#pragma unroll
  for (int o = 1; o < 256; o <<= 1) {
    int add = (t >= o) ? ts[t - o] : 0;
    __syncthreads();
    ts[t] += add;
    __syncthreads();
  }
  int off = off0 + (t ? ts[t - 1] : 0);
  int4 o4 = make_int4(off, off + s0, off + s01, off + s012);
  *(int4*)&indptr[base] = o4;
  *(int4*)&cursor[base] = o4;
}

// ---------------- fused scatter: rel slots (slotOf,srcR,dstOf) + dst-CSR (esortD) ----------------
__global__ void k_scatter_both(const int* __restrict__ dst, const int* __restrict__ et,
                               const int* __restrict__ src, int* __restrict__ curR,
                               int* __restrict__ curN, int* __restrict__ slotOf,
                               int* __restrict__ srcR, int* __restrict__ dstOf,
                               int* __restrict__ esortD) {
  int e = blockIdx.x * blockDim.x + threadIdx.x;
  if (e < E_) {
    int d = dst[e];
    int p = atomicAdd(&curR[et[e] * N_ + d], 1);
    slotOf[e] = p;
    srcR[p] = src[e];
    int p2 = atomicAdd(&curN[d], 1);
    esortD[p2] = e;
    dstOf[p] = p2;   // rel-slot -> dst-slot (m rows land dst-contiguous)
  }
}

// ---------------- WQK for ALL layers: wave per (l,r,d) row ----------------
__global__ __launch_bounds__(256) void k_wqk_all(const float* __restrict__ W,
                                                 const float* __restrict__ Q,
                                                 const float* __restrict__ Km,
                                                 float* __restrict__ WQK) {
  int gw = (blockIdx.x * 256 + threadIdx.x) >> 6;  // 0..L*R*D-1 = 4095
  int lane = threadIdx.x & 63;
  int d = gw & 127, r = (gw >> 7) & 7, l = gw >> 10;
  const float* wrow = W + (((size_t)l * R_ + r) * D_ + d) * HK_;
  const float* Ql = Q + (size_t)l * HK_ * H_;
  const float* Kl = Km + (size_t)l * HK_ * H_;
  float acc[8] = {0.f, 0.f, 0.f, 0.f, 0.f, 0.f, 0.f, 0.f};
#pragma unroll
  for (int it = 0; it < 8; ++it) {
    int k = it * 64 + lane;
    float w = wrow[k];
    const float4 qv = *(const float4*)&Ql[k * 4];
    const float4 kv = *(const float4*)&Kl[k * 4];
    acc[0] += w * qv.x; acc[1] += w * qv.y; acc[2] += w * qv.z; acc[3] += w * qv.w;
    acc[4] += w * kv.x; acc[5] += w * kv.y; acc[6] += w * kv.z; acc[7] += w * kv.w;
  }
#pragma unroll
  for (int o = 32; o; o >>= 1)
#pragma unroll
    for (int j = 0; j < 8; ++j) acc[j] += __shfl_down(acc[j], o, 64);
  if (lane == 0) {
#pragma unroll
    for (int h = 0; h < 4; ++h) {
      WQK[((size_t)l * D_ + d) * 64 + r * 4 + h] = acc[h];
      WQK[((size_t)l * D_ + d) * 64 + 32 + r * 4 + h] = acc[4 + h];
    }
  }
}

// ---------------- fused embed + layer-0 q,k (32 nodes/block) ----------------
__global__ __launch_bounds__(256) void k_embed_qk(
    const int* __restrict__ xn, const float* __restrict__ emb,
    const float* __restrict__ WQK, float* __restrict__ x, u16* __restrict__ xb,
    float* __restrict__ q, float* __restrict__ kk) {
  __shared__ float xs[32][129];
  __shared__ float wq[128][64];
  __shared__ int xnl[32];
  const int t = threadIdx.x;
  const int n0 = blockIdx.x * 32;
  if (t < 32) xnl[t] = xn[n0 + t];
#pragma unroll
  for (int p = 0; p < 8; ++p) {
    int idx = t + p * 256;
    int row = idx >> 4, c4 = (idx & 15) * 4;
    *(float4*)&wq[row][c4] = *(const float4*)&WQK[row * 64 + c4];
  }
  __syncthreads();
#pragma unroll
  for (int p = 0; p < 16; ++p) {      // 4096 elems of x
    int idx = t + p * 256;
    int node = idx >> 7, d = idx & 127;
    float v = emb[xnl[node] * D_ + d];
    xs[node][d] = v;
    x[(size_t)(n0 + node) * D_ + d] = v;
    xb[(size_t)(n0 + node) * D_ + d] = bfr(v);
  }
  __syncthreads();
  const int node = t >> 3, cq = t & 7;
  float s[8];
#pragma unroll
  for (int j = 0; j < 8; ++j) s[j] = 0.f;
  for (int k = 0; k < 128; ++k) {
    float xv = xs[node][k];
#pragma unroll
    for (int j = 0; j < 8; ++j) s[j] = fmaf(xv, wq[k][cq * 8 + j], s[j]);
  }
#pragma unroll
  for (int j = 0; j < 8; ++j) {
    int c = cq * 8 + j;
    if (c < 32) q[(size_t)(n0 + node) * 32 + c] = s[j];
    else        kk[(size_t)(n0 + node) * 32 + (c - 32)] = s[j];
  }
}

// ---------------- fused attention softmax: wave per dst node, normalized aw out ----------------
__global__ __launch_bounds__(256) void k_attn(
    const int* __restrict__ ipN, const int* __restrict__ esD,
    const int* __restrict__ src, const int* __restrict__ et,
    const float* __restrict__ q, const float* __restrict__ kk,
    const int* __restrict__ slotOf, float* __restrict__ aw) {
  int n = blockIdx.x * 4 + (threadIdx.x >> 6);
  int lane = threadIdx.x & 63;
  int j0 = ipN[n], j1 = ipN[n + 1];
  int deg = j1 - j0;
  if (deg == 0) return;            // wave-uniform
  int h = lane & 3;
  if (deg <= 16) {                 // fast path (covers most nodes)
    int ei = lane >> 2;
    float a = -3.4e38f;
    int slot = 0;
    if (ei < deg) {
      int e = esD[j0 + ei];
      int r = et[e];
      slot = slotOf[e];
      a = lrelu(q[(size_t)n * 32 + r * 4 + h] + kk[(size_t)src[e] * 32 + r * 4 + h]);
    }
    float m = a;
#pragma unroll
    for (int o = 4; o < 64; o <<= 1) m = fmaxf(m, __shfl_xor(m, o, 64));
    float ex = (ei < deg) ? expf(a - m) : 0.f;
    float s = ex;
#pragma unroll
    for (int o = 4; o < 64; o <<= 1) s += __shfl_xor(s, o, 64);
    if (ei < deg) aw[(size_t)slot * 4 + h] = ex * (0.25f / (s + 1e-16f));
    return;
  }
  // general path (rare)
  int nch = (deg + 15) >> 4;
  float m = -3.4e38f;
  for (int c = 0; c < nch; ++c) {
    int ei = c * 16 + (lane >> 2);
    if (ei < deg) {
      int e = esD[j0 + ei];
      int r = et[e];
      float a = lrelu(q[(size_t)n * 32 + r * 4 + h] + kk[(size_t)src[e] * 32 + r * 4 + h]);
      m = fmaxf(m, a);
    }
  }
#pragma unroll
  for (int o = 4; o < 64; o <<= 1) m = fmaxf(m, __shfl_xor(m, o, 64));
  float s = 0.f;
  for (int c = 0; c < nch; ++c) {
    int ei = c * 16 + (lane >> 2);
    if (ei < deg) {
      int e = esD[j0 + ei];
      int r = et[e];
      float a = lrelu(q[(size_t)n * 32 + r * 4 + h] + kk[(size_t)src[e] * 32 + r * 4 + h]);
      float ex = expf(a - m);
      s += ex;
      aw[(size_t)slotOf[e] * 4 + h] = ex;
    }
  }
#pragma unroll
  for (int o = 4; o < 64; o <<= 1) s += __shfl_xor(s, o, 64);
  float inv = 0.25f / (s + 1e-16f);
  for (int c = 0; c < nch; ++c) {
    int ei = c * 16 + (lane >> 2);
    if (ei < deg) {
      int e = esD[j0 + ei];
      aw[(size_t)slotOf[e] * 4 + h] *= inv;
    }
  }
}

// W fp32 [L][R][D][HK] -> wt bf16 [L][R][HK][D]  (all layers, z = l*R+r)
__global__ void k_cvt_w_all(const float* __restrict__ W, u16* __restrict__ wt) {
  __shared__ u16 tile[64][65];
  const int z = blockIdx.z, k0 = blockIdx.y * 64, c0 = blockIdx.x * 64;
  const int t = threadIdx.x;
  const int tk = t >> 4, tc4 = (t & 15) * 4;
  const float* Wz = W + (size_t)z * D_ * HK_;
  u16* wz = wt + (size_t)z * HK_ * D_;
#pragma unroll
  for (int p = 0; p < 4; ++p) {
    int krow = tk + p * 16;
    const float4 v = *(const float4*)&Wz[(size_t)(k0 + krow) * HK_ + c0 + tc4];
    tile[tc4 + 0][krow] = bfr(v.x);
    tile[tc4 + 1][krow] = bfr(v.y);
    tile[tc4 + 2][krow] = bfr(v.z);
    tile[tc4 + 3][krow] = bfr(v.w);
  }
  __syncthreads();
#pragma unroll
  for (int p = 0; p < 4; ++p) {
    int crow = tk + p * 16;
    uint2 o;
    o.x = (u32)tile[crow][tc4 + 0] | ((u32)tile[crow][tc4 + 1] << 16);
    o.y = (u32)tile[crow][tc4 + 2] | ((u32)tile[crow][tc4 + 3] << 16);
    *(uint2*)&wz[(size_t)(c0 + crow) * D_ + k0 + tc4] = o;
  }
}

// ---------------- edge-GEMM v8d: r15 structure + dst-slot message stores ----------------
// Identical compute to proven-best r15 k_edge8; only phase-B row destinations are
// permuted to dst-CSR order so k_aggqk reads contiguous per-node runs.
__global__ __launch_bounds__(512, 1) void k_edge8(
    const u16* __restrict__ xb, const u16* __restrict__ wt,   // wt: layer base [R][HK][D]
    const int* __restrict__ indptrR, const int* __restrict__ padBase,
    const int* __restrict__ srcR, const int* __restrict__ dstOf,
    const float* __restrict__ aw, u16* __restrict__ m) {
  __shared__ u16 atile[128 * 128];     // 32 KB, XOR-swizzled
  __shared__ u16 outb[128 * 128];      // 32 KB, epilogue staging (no post-MFMA barrier)
  __shared__ float awl[128][4];
  __shared__ int srcl[128];
  __shared__ int dsl[128];
  const int t = threadIdx.x;
  const int b128 = blockIdx.x * 128;
  if (b128 >= padBase[R_]) return;     // block-uniform tail guard
  int r = 0;
  while (b128 >= padBase[r + 1]) ++r;  // block-uniform, <=8 iters
  const int ip0 = indptrR[r * N_];
  const int cnt = indptrR[(r + 1) * N_] - ip0;
  const int local0 = b128 - padBase[r];
  const u16* wrp = wt + (size_t)r * HK_ * D_;
  const int wid = t >> 6, lane = t & 63;
  const int l15 = lane & 15, l4 = lane >> 4;
  // B-frags issued FIRST (L2-hot; latency overlaps meta + A-gather)
  short8 breg[4][4];                   // [ks][h]
#pragma unroll
  for (int ks = 0; ks < 4; ++ks)
#pragma unroll
    for (int h = 0; h < 4; ++h) {
      int c = (wid + 8 * h) * 16 + l15;
      breg[ks][h] = *(const short8*)(wrp + (size_t)c * 128 + ks * 32 + l4 * 8);
    }
  // meta (rel-sorted slots: coalesced)
  if (t < 128) {
    int lidx = local0 + t;
    if (lidx < cnt) {
      srcl[t] = srcR[ip0 + lidx];
      dsl[t] = dstOf[ip0 + lidx];
      *(float4*)awl[t] = *(const float4*)(aw + (size_t)(ip0 + lidx) * 4);
    } else {
      srcl[t] = 0;
      dsl[t] = -1;
      *(float4*)awl[t] = make_float4(0.f, 0.f, 0.f, 0.f);
    }
  }
  __syncthreads();   // meta visible
  // A gather -> LDS (4 uint4/thread; 16 lanes per row)
#pragma unroll
  for (int p = 0; p < 4; ++p) {
    int idx = t + p * 512;
    int row = idx >> 4, seg = idx & 15;
    uint4 v = *(const uint4*)(xb + (size_t)srcl[row] * 128 + seg * 8);
    *(uint4*)((char*)atile + row * 256 + ((seg * 16) ^ ((row & 7) << 4))) = v;
  }
  __syncthreads();   // A visible
  // MFMA: 128 rows x 16 out-cols (4 orig colfrags) x K=128 -> 128 MFMA/wave
  f32x4 acc[8][4];                     // [row i][h]
#pragma unroll
  for (int i = 0; i < 8; ++i)
#pragma unroll
    for (int h = 0; h < 4; ++h) acc[i][h] = (f32x4){0.f, 0.f, 0.f, 0.f};
#pragma unroll
  for (int ks = 0; ks < 4; ++ks) {
    short8 av[8];
#pragma unroll
    for (int i = 0; i < 8; ++i) {
      int row = i * 16 + l15;
      av[i] = *(const short8*)((char*)atile + row * 256 +
                ((l4 * 16 + ks * 64) ^ ((row & 7) << 4)));
    }
#pragma unroll
    for (int i = 0; i < 8; ++i)
#pragma unroll
      for (int h = 0; h < 4; ++h)
        // swapped operands: lane holds row = i*16+l15, cols (wid+8h)*16 + l4*4 + rg
        acc[i][h] = __builtin_amdgcn_mfma_f32_16x16x32_bf16(breg[ks][h], av[i],
                                                            acc[i][h], 0, 0, 0);
  }
  // epilogue phase A: head-reduce -> outb (separate region: no barrier needed here)
#pragma unroll
  for (int i = 0; i < 8; ++i) {
    int row = i * 16 + l15;
    const float4 awf = *(const float4*)awl[row];
    float v0 = awf.x * acc[i][0][0] + awf.y * acc[i][1][0] + awf.z * acc[i][2][0] + awf.w * acc[i][3][0];
    float v1 = awf.x * acc[i][0][1] + awf.y * acc[i][1][1] + awf.z * acc[i][2][1] + awf.w * acc[i][3][1];
    float v2 = awf.x * acc[i][0][2] + awf.y * acc[i][1][2] + awf.z * acc[i][2][2] + awf.w * acc[i][3][2];
    float v3 = awf.x * acc[i][0][3] + awf.y * acc[i][1][3] + awf.z * acc[i][2][3] + awf.w * acc[i][3][3];
    uint2 o;
    o.x = (u32)bfr(v0) | ((u32)bfr(v1) << 16);
    o.y = (u32)bfr(v2) | ((u32)bfr(v3) << 16);
    *(uint2*)((char*)outb + row * 256 + ((wid * 32 + l4 * 8) ^ ((row & 7) << 4))) = o;
  }
  __syncthreads();   // outb complete across waves
  // phase B: full-line stores to dst-slot rows (256B contiguous per row)
  {
    int row = t >> 2, c0 = (t & 3) * 64;   // byte offsets within 256B row
    int slot = dsl[row];
    if (slot >= 0) {
      char* gout = (char*)(m + (size_t)slot * 128) + c0;
#pragma unroll
      for (int qq = 0; qq < 4; ++qq) {
        uint4 v = *(const uint4*)((char*)outb + row * 256 + ((c0 + qq * 16) ^ ((row & 7) << 4)));
        *(uint4*)(gout + qq * 16) = v;
      }
    }
  }
}

// ---------------- fused: aggregate (dst-contiguous rows) + bias/relu + x/xb + next q,k ----------------
__global__ __launch_bounds__(256) void k_aggqk(
    const int* __restrict__ ipN, const u16* __restrict__ m,
    const float* __restrict__ Bl, const float* __restrict__ WQK, int doqk,
    float* __restrict__ xout, u16* __restrict__ xbout,
    float* __restrict__ q, float* __restrict__ kk) {
  __shared__ float wqs[128 * 64];      // 32 KB
  __shared__ float xrow[4][128];
  const int t = threadIdx.x;
  if (doqk) {
#pragma unroll
    for (int p = 0; p < 8; ++p)
      *(float4*)&wqs[(t + p * 256) * 4] = *(const float4*)&WQK[(t + p * 256) * 4];
  }
  const int w = t >> 6;
  int n = blockIdx.x * 4 + w;
  int lane = t & 63;
  int j0 = ipN[n], j1 = ipN[n + 1];
  float s0 = 0.f, s1 = 0.f;   // d = 2*lane, 2*lane+1
  int j = j0;
  for (; j + 1 < j1; j += 2) {          // contiguous rows; 2-wide load ILP
    u32 v0 = *((const u32*)(m + (size_t)j * 128) + lane);
    u32 v1 = *((const u32*)(m + (size_t)(j + 1) * 128) + lane);
    s0 += bf2f(v0 & 0xffffu) + bf2f(v1 & 0xffffu);
    s1 += bf2f(v0 >> 16) + bf2f(v1 >> 16);
  }
  if (j < j1) {
    u32 v0 = *((const u32*)(m + (size_t)j * 128) + lane);
    s0 += bf2f(v0 & 0xffffu);
    s1 += bf2f(v0 >> 16);
  }
  float2 o;
  o.x = fmaxf(s0 + Bl[2 * lane], 0.f);
  o.y = fmaxf(s1 + Bl[2 * lane + 1], 0.f);
  *((float2*)(xout + (size_t)n * D_) + lane) = o;
  ((u32*)(xbout + (size_t)n * D_))[lane] = (u32)bfr(o.x) | ((u32)bfr(o.y) << 16);
  if (doqk) {
    xrow[w][2 * lane] = o.x;
    xrow[w][2 * lane + 1] = o.y;
    __syncthreads();   // wqs + xrow visible (doqk is uniform kernel arg)
    const float* xr = xrow[w];
    float s = 0.f;
#pragma unroll
    for (int d4 = 0; d4 < 32; ++d4) {
      const float4 xv = *(const float4*)&xr[d4 * 4];
      s += xv.x * wqs[(d4 * 4 + 0) * 64 + lane] + xv.y * wqs[(d4 * 4 + 1) * 64 + lane] +
           xv.z * wqs[(d4 * 4 + 2) * 64 + lane] + xv.w * wqs[(d4 * 4 + 3) * 64 + lane];
    }
    if (lane < 32) q[(size_t)n * 32 + lane] = s;
    else           kk[(size_t)n * 32 + (lane - 32)] = s;
  }
}

// ---------------- graph mean-pool ----------------
__global__ void k_pool(const float* __restrict__ x, float* __restrict__ pooled) {
  int i = blockIdx.x * blockDim.x + threadIdx.x; // G*D
  if (i >= G_ * D_) return;
  int d = i & 127, g = i >> 7;
  float s = 0.f;
  for (int j = 0; j < NPG_; ++j) s += x[(size_t)(g * NPG_ + j) * D_ + d];
  pooled[i] = s * (1.0f / NPG_);
}

// ---------------- head MLP ----------------
__global__ void k_head(const float* __restrict__ pooled, const float* __restrict__ fc1w,
                       const float* __restrict__ fc1b, const float* __restrict__ polw,
                       const float* __restrict__ polb, const float* __restrict__ valw,
                       const float* __restrict__ valb, float* __restrict__ out) {
  int g = blockIdx.x;
  int t = threadIdx.x; // 64
  __shared__ float hb[64];
  const float* p = pooled + (size_t)g * D_;
  float s = fc1b[t];
  for (int d = 0; d < D_; ++d) s += p[d] * fc1w[d * 64 + t];
  hb[t] = fmaxf(s, 0.f);
  __syncthreads();
  if (t < 7) {
    float s2 = polb[t];
    for (int j = 0; j < 64; ++j) s2 += hb[j] * polw[j * 7 + t];
    out[g * 7 + t] = s2;
  } else if (t == 7) {
    float s2 = valb[0];
    for (int j = 0; j < 64; ++j) s2 += hb[j] * valw[j];
    out[G_ * 7 + g] = tanhf(s2);
  }
}

extern "C" void kernel_launch(void* const* d_in, const int* in_sizes, int n_in,
                              void* d_out, int out_size, void* d_ws, size_t ws_size,
                              hipStream_t stream) {
  (void)in_sizes; (void)n_in; (void)out_size;
  const int*   x_nodes = (const int*)d_in[0];
  const int*   eidx    = (const int*)d_in[1];
  const int*   etype   = (const int*)d_in[2];
  const float* emb     = (const float*)d_in[4];
  const float* W       = (const float*)d_in[5];
  const float* Q       = (const float*)d_in[6];
  const float* Km      = (const float*)d_in[7];
  const float* B       = (const float*)d_in[8];
  const float* fc1w    = (const float*)d_in[9];
  const float* fc1b    = (const float*)d_in[10];
  const float* polw    = (const float*)d_in[11];
  const float* polb    = (const float*)d_in[12];
  const float* valw    = (const float*)d_in[13];
  const float* valb    = (const float*)d_in[14];
  float* out = (float*)d_out;
  const int* srcA = eidx;        // edge_index[0,:]
  const int* dstA = eidx + E_;   // edge_index[1,:]

  char* p = (char*)d_ws;
  size_t used = 0;
  auto carve = [&](size_t bytes) {
    char* q = p;
    size_t adv = (bytes + 255) & ~(size_t)255;
    p += adv;
    used += adv;
    return q;
  };
  float* x_cur  = (float*)carve((size_t)N_ * D_ * 4);            // 10.5 MB
  float* x_nxt  = (float*)carve((size_t)N_ * D_ * 4);            // 10.5 MB
  u16*   xbf    = (u16*)carve((size_t)N_ * D_ * 2);              // 5.2 MB
  u16*   mbuf   = (u16*)carve((size_t)E_ * D_ * 2);              // 41.9 MB (exact E rows)
  float* qbuf   = (float*)carve((size_t)N_ * 32 * 4);            // 2.6 MB
  float* kbuf   = (float*)carve((size_t)N_ * 32 * 4);            // 2.6 MB
  float* awbuf  = (float*)carve((size_t)E_ * H_ * 4);            // 2.6 MB
  float* WQKb   = (float*)carve((size_t)L_ * D_ * 64 * 4);       // 131 KB
  u16*   Wtb    = (u16*)carve((size_t)L_ * R_ * HK_ * D_ * 2);   // 4.2 MB
  float* pooled = (float*)carve((size_t)G_ * D_ * 4);
  int* countsR  = (int*)carve((size_t)R_ * N_ * 4);
  int* cursorR  = (int*)carve((size_t)R_ * N_ * 4);
  int* indptrR  = (int*)carve((size_t)(R_ * N_ + 1) * 4);
  int* slotOf   = (int*)carve((size_t)E_ * 4);
  int* srcR     = (int*)carve((size_t)E_ * 4);
  int* dstOf    = (int*)carve((size_t)E_ * 4);
  int* countsN  = (int*)carve((size_t)N_ * 4);
  int* cursorN  = (int*)carve((size_t)N_ * 4);
  int* indptrN  = (int*)carve((size_t)(N_ + 1) * 4);
  int* esortD   = (int*)carve((size_t)E_ * 4);
  int* padBase  = (int*)carve((size_t)(R_ + 1) * 4);
  int* bsumR    = (int*)carve((size_t)160 * 4);
  int* bsumN    = (int*)carve((size_t)32 * 4);
  if (used > ws_size) return;  // defensive: fail via poisoned output, not OOB crash

  constexpr int RN = R_ * N_;          // 163840
  constexpr int EDGE_BLOCKS = E_ / 128 + R_;  // 1288 (covers padding)

  // ---- fused CSR builds + one-time precomputes (9 setup dispatches) ----
  k_zero2<<<(RN + N_ + 255) / 256, 256, 0, stream>>>(countsR, countsN);
  k_count_both<<<E_ / 256, 256, 0, stream>>>(dstA, etype, countsR, countsN);
  k_bsum2<<<180, 256, 0, stream>>>(countsR, countsN, bsumR, bsumN);
  k_bscan2<<<1, 256, 0, stream>>>(bsumR, bsumN, indptrR + RN, indptrN + N_, padBase);
  k_scan32<<<180, 256, 0, stream>>>(countsR, countsN, bsumR, bsumN,
                                    indptrR, cursorR, indptrN, cursorN);
  k_scatter_both<<<E_ / 256, 256, 0, stream>>>(dstA, etype, srcA, cursorR, cursorN,
                                               slotOf, srcR, dstOf, esortD);
  k_wqk_all<<<(L_ * R_ * D_ * 64) / 256, 256, 0, stream>>>(W, Q, Km, WQKb);
  k_cvt_w_all<<<dim3(HK_ / 64, D_ / 64, L_ * R_), 256, 0, stream>>>(W, Wtb);
  k_embed_qk<<<N_ / 32, 256, 0, stream>>>(x_nodes, emb, WQKb, x_cur, xbf, qbuf, kbuf);

  for (int l = 0; l < L_; ++l) {
    const float* Bl = B + (size_t)l * D_;
    k_attn<<<N_ / 4, 256, 0, stream>>>(indptrN, esortD, srcA, etype, qbuf, kbuf,
                                       slotOf, awbuf);
    k_edge8<<<EDGE_BLOCKS, 512, 0, stream>>>(xbf, Wtb + (size_t)l * R_ * HK_ * D_,
                                             indptrR, padBase, srcR, dstOf, awbuf, mbuf);
    int doqk = (l < L_ - 1) ? 1 : 0;
    k_aggqk<<<N_ / 4, 256, 0, stream>>>(indptrN, mbuf, Bl,
                                        WQKb + (size_t)(l + 1) * D_ * 64 * (doqk ? 1 : 0),
                                        doqk, x_nxt, xbf, qbuf, kbuf);
    float* tmp = x_cur; x_cur = x_nxt; x_nxt = tmp;
  }

  k_pool<<<(G_ * D_) / 256, 256, 0, stream>>>(x_cur, pooled);
  k_head<<<G_, 64, 0, stream>>>(pooled, fc1w, fc1b, polw, polb, valw, valb, out);
}

// Round 20
// 443.975 us; speedup vs baseline: 1.3651x; 1.0231x over previous
//
#include <hip/hip_runtime.h>
#include <cstdint>
#include <cstddef>

constexpr int N_  = 20480;
constexpr int E_  = 163840;
constexpr int G_  = 512;
constexpr int D_  = 128;
constexpr int H_  = 4;
constexpr int R_  = 8;
constexpr int L_  = 4;
constexpr int HK_ = 512;   // H*D
constexpr int NPG_ = N_ / G_; // 40

typedef short short8 __attribute__((ext_vector_type(8)));
typedef float f32x4 __attribute__((ext_vector_type(4)));
typedef unsigned short u16;
typedef unsigned int u32;

__device__ inline u16 bfr(float f) {  // fp32 -> bf16 RNE
  u32 u = __builtin_bit_cast(u32, f);
  return (u16)((u + 0x7fffu + ((u >> 16) & 1u)) >> 16);
}
__device__ inline float bf2f(u32 lo16) { return __builtin_bit_cast(float, lo16 << 16); }
__device__ inline float lrelu(float v) { return v >= 0.f ? v : 0.2f * v; }

// ---------------- fused zero: countsR (RN) + countsN (N) ----------------
__global__ void k_zero2(int* __restrict__ cR, int* __restrict__ cN) {
  int i = blockIdx.x * blockDim.x + threadIdx.x;
  if (i < R_ * N_) cR[i] = 0;
  else if (i < R_ * N_ + N_) cN[i - R_ * N_] = 0;
}

// ---------------- fused count: rel-CSR + dst-CSR ----------------
__global__ void k_count_both(const int* __restrict__ dst, const int* __restrict__ et,
                             int* __restrict__ cR, int* __restrict__ cN) {
  int e = blockIdx.x * blockDim.x + threadIdx.x;
  if (e < E_) {
    int d = dst[e];
    atomicAdd(&cR[et[e] * N_ + d], 1);
    atomicAdd(&cN[d], 1);
  }
}

// ---------------- fused per-block sums ----------------
__global__ void k_bsum2(const int* __restrict__ cR, const int* __restrict__ cN,
                        int* __restrict__ bsumR, int* __restrict__ bsumN) {
  int b = blockIdx.x;
  const int* src = (b < 160) ? &cR[b * 1024] : &cN[(b - 160) * 1024];
  int t = threadIdx.x;
  const int4 v = *(const int4*)&src[t * 4];
  int s = v.x + v.y + v.z + v.w;
#pragma unroll
  for (int o = 32; o; o >>= 1) s += __shfl_down(s, o, 64);
  __shared__ int ws_[4];
  if ((t & 63) == 0) ws_[t >> 6] = s;
  __syncthreads();
  if (t == 0) {
    int tot = ws_[0] + ws_[1] + ws_[2] + ws_[3];
    if (b < 160) bsumR[b] = tot; else bsumN[b - 160] = tot;
  }
}

// ---------------- fused block-sum scan + totals + padBase (r6 lesson: totals MUST be written) ----------------
__global__ void k_bscan2(int* __restrict__ bsumR, int* __restrict__ bsumN,
                         int* __restrict__ totR, int* __restrict__ totN,
                         int* __restrict__ padBase) {
  __shared__ int shR[160];
  __shared__ int shN[20];
  int t = threadIdx.x;
  if (t < 160) shR[t] = bsumR[t];
  if (t < 20) shN[t] = bsumN[t];
  __syncthreads();
  if (t == 0) {
    int run = 0;
    for (int i = 0; i < 160; ++i) { int v = shR[i]; shR[i] = run; run += v; }
    totR[0] = run;   // = E
    int cum = 0;
    for (int r = 0; r < R_; ++r) {          // padBase from relation boundaries (block r*20)
      padBase[r] = cum;
      int lo = shR[r * 20];
      int hi = (r == R_ - 1) ? run : shR[(r + 1) * 20];
      cum += (hi - lo + 127) & ~127;
    }
    padBase[R_] = cum;
    int run2 = 0;
    for (int i = 0; i < 20; ++i) { int v = shN[i]; shN[i] = run2; run2 += v; }
    totN[0] = run2;  // = E
  }
  __syncthreads();
  if (t < 160) bsumR[t] = shR[t];
  if (t < 20) bsumN[t] = shN[t];
}

// ---------------- fused full scan write ----------------
__global__ void k_scan32(const int* __restrict__ cR, const int* __restrict__ cN,
                         const int* __restrict__ bsumR, const int* __restrict__ bsumN,
                         int* __restrict__ ipR, int* __restrict__ curR,
                         int* __restrict__ ipN, int* __restrict__ curN) {
  __shared__ int ts[256];
  int b = blockIdx.x;
  const int* c;
  int off0;
  int* indptr;
  int* cursor;
  int lb;
  if (b < 160) { c = cR; off0 = bsumR[b]; indptr = ipR; cursor = curR; lb = b; }
  else { c = cN; off0 = bsumN[b - 160]; indptr = ipN; cursor = curN; lb = b - 160; }
  int t = threadIdx.x;
  int base = lb * 1024 + t * 4;
  const int4 v = *(const int4*)&c[base];
  int s0 = v.x, s01 = v.x + v.y, s012 = s01 + v.z, s = s012 + v.w;
  ts[t] = s;
  __syncthreads();
#pragma unroll
  for (int o = 1; o < 256; o <<= 1) {
    int add = (t >= o) ? ts[t - o] : 0;
    __syncthreads();
    ts[t] += add;
    __syncthreads();
  }
  int off = off0 + (t ? ts[t - 1] : 0);
  int4 o4 = make_int4(off, off + s0, off + s01, off + s012);
  *(int4*)&indptr[base] = o4;
  *(int4*)&cursor[base] = o4;
}

// ---------------- fused scatter: rel slots (srcR,dstOf) + dst-ordered meta (srcD,rsD) ----------------
__global__ void k_scatter_both(const int* __restrict__ dst, const int* __restrict__ et,
                               const int* __restrict__ src, int* __restrict__ curR,
                               int* __restrict__ curN, int* __restrict__ srcR,
                               int* __restrict__ dstOf, int* __restrict__ srcD,
                               int* __restrict__ rsD) {
  int e = blockIdx.x * blockDim.x + threadIdx.x;
  if (e < E_) {
    int d = dst[e];
    int r = et[e];
    int s = src[e];
    int p = atomicAdd(&curR[r * N_ + d], 1);
    srcR[p] = s;
    int p2 = atomicAdd(&curN[d], 1);
    dstOf[p] = p2;                 // rel-slot -> dst-slot (m rows land dst-contiguous)
    srcD[p2] = s;                  // dst-ordered src (contiguous reads in k_attn)
    rsD[p2] = (p << 3) | r;        // dst-ordered {rel-slot, relation} packed
  }
}

// ---------------- WQK for ALL layers: wave per (l,r,d) row ----------------
__global__ __launch_bounds__(256) void k_wqk_all(const float* __restrict__ W,
                                                 const float* __restrict__ Q,
                                                 const float* __restrict__ Km,
                                                 float* __restrict__ WQK) {
  int gw = (blockIdx.x * 256 + threadIdx.x) >> 6;  // 0..L*R*D-1 = 4095
  int lane = threadIdx.x & 63;
  int d = gw & 127, r = (gw >> 7) & 7, l = gw >> 10;
  const float* wrow = W + (((size_t)l * R_ + r) * D_ + d) * HK_;
  const float* Ql = Q + (size_t)l * HK_ * H_;
  const float* Kl = Km + (size_t)l * HK_ * H_;
  float acc[8] = {0.f, 0.f, 0.f, 0.f, 0.f, 0.f, 0.f, 0.f};
#pragma unroll
  for (int it = 0; it < 8; ++it) {
    int k = it * 64 + lane;
    float w = wrow[k];
    const float4 qv = *(const float4*)&Ql[k * 4];
    const float4 kv = *(const float4*)&Kl[k * 4];
    acc[0] += w * qv.x; acc[1] += w * qv.y; acc[2] += w * qv.z; acc[3] += w * qv.w;
    acc[4] += w * kv.x; acc[5] += w * kv.y; acc[6] += w * kv.z; acc[7] += w * kv.w;
  }
#pragma unroll
  for (int o = 32; o; o >>= 1)
#pragma unroll
    for (int j = 0; j < 8; ++j) acc[j] += __shfl_down(acc[j], o, 64);
  if (lane == 0) {
#pragma unroll
    for (int h = 0; h < 4; ++h) {
      WQK[((size_t)l * D_ + d) * 64 + r * 4 + h] = acc[h];
      WQK[((size_t)l * D_ + d) * 64 + 32 + r * 4 + h] = acc[4 + h];
    }
  }
}

// ---------------- fused embed + layer-0 q,k (32 nodes/block) ----------------
__global__ __launch_bounds__(256) void k_embed_qk(
    const int* __restrict__ xn, const float* __restrict__ emb,
    const float* __restrict__ WQK, float* __restrict__ x, u16* __restrict__ xb,
    float* __restrict__ q, float* __restrict__ kk) {
  __shared__ float xs[32][129];
  __shared__ float wq[128][64];
  __shared__ int xnl[32];
  const int t = threadIdx.x;
  const int n0 = blockIdx.x * 32;
  if (t < 32) xnl[t] = xn[n0 + t];
#pragma unroll
  for (int p = 0; p < 8; ++p) {
    int idx = t + p * 256;
    int row = idx >> 4, c4 = (idx & 15) * 4;
    *(float4*)&wq[row][c4] = *(const float4*)&WQK[row * 64 + c4];
  }
  __syncthreads();
#pragma unroll
  for (int p = 0; p < 16; ++p) {      // 4096 elems of x
    int idx = t + p * 256;
    int node = idx >> 7, d = idx & 127;
    float v = emb[xnl[node] * D_ + d];
    xs[node][d] = v;
    x[(size_t)(n0 + node) * D_ + d] = v;
    xb[(size_t)(n0 + node) * D_ + d] = bfr(v);
  }
  __syncthreads();
  const int node = t >> 3, cq = t & 7;
  float s[8];
#pragma unroll
  for (int j = 0; j < 8; ++j) s[j] = 0.f;
  for (int k = 0; k < 128; ++k) {
    float xv = xs[node][k];
#pragma unroll
    for (int j = 0; j < 8; ++j) s[j] = fmaf(xv, wq[k][cq * 8 + j], s[j]);
  }
#pragma unroll
  for (int j = 0; j < 8; ++j) {
    int c = cq * 8 + j;
    if (c < 32) q[(size_t)(n0 + node) * 32 + c] = s[j];
    else        kk[(size_t)(n0 + node) * 32 + (c - 32)] = s[j];
  }
}

// ---------------- attention softmax: wave per dst node; contiguous dst-ordered meta ----------------
__global__ __launch_bounds__(256) void k_attn(
    const int* __restrict__ ipN, const int* __restrict__ srcD,
    const int* __restrict__ rsD, const float* __restrict__ q,
    const float* __restrict__ kk, float* __restrict__ aw) {
  int n = blockIdx.x * 4 + (threadIdx.x >> 6);
  int lane = threadIdx.x & 63;
  int j0 = ipN[n], j1 = ipN[n + 1];
  int deg = j1 - j0;
  if (deg == 0) return;            // wave-uniform
  int h = lane & 3;
  if (deg <= 16) {                 // fast path (covers most nodes)
    int ei = lane >> 2;
    float a = -3.4e38f;
    int slot = 0;
    if (ei < deg) {
      int sr = rsD[j0 + ei];       // contiguous
      int s = srcD[j0 + ei];       // contiguous
      int r = sr & 7;
      slot = sr >> 3;
      a = lrelu(q[(size_t)n * 32 + r * 4 + h] + kk[(size_t)s * 32 + r * 4 + h]);
    }
    float m = a;
#pragma unroll
    for (int o = 4; o < 64; o <<= 1) m = fmaxf(m, __shfl_xor(m, o, 64));
    float ex = (ei < deg) ? expf(a - m) : 0.f;
    float s = ex;
#pragma unroll
    for (int o = 4; o < 64; o <<= 1) s += __shfl_xor(s, o, 64);
    if (ei < deg) aw[(size_t)slot * 4 + h] = ex * (0.25f / (s + 1e-16f));
    return;
  }
  // general path (rare)
  int nch = (deg + 15) >> 4;
  float m = -3.4e38f;
  for (int c = 0; c < nch; ++c) {
    int ei = c * 16 + (lane >> 2);
    if (ei < deg) {
      int sr = rsD[j0 + ei];
      int s = srcD[j0 + ei];
      int r = sr & 7;
      float a = lrelu(q[(size_t)n * 32 + r * 4 + h] + kk[(size_t)s * 32 + r * 4 + h]);
      m = fmaxf(m, a);
    }
  }
#pragma unroll
  for (int o = 4; o < 64; o <<= 1) m = fmaxf(m, __shfl_xor(m, o, 64));
  float s = 0.f;
  for (int c = 0; c < nch; ++c) {
    int ei = c * 16 + (lane >> 2);
    if (ei < deg) {
      int sr = rsD[j0 + ei];
      int sn = srcD[j0 + ei];
      int r = sr & 7;
      float a = lrelu(q[(size_t)n * 32 + r * 4 + h] + kk[(size_t)sn * 32 + r * 4 + h]);
      float ex = expf(a - m);
      s += ex;
      aw[(size_t)(sr >> 3) * 4 + h] = ex;
    }
  }
#pragma unroll
  for (int o = 4; o < 64; o <<= 1) s += __shfl_xor(s, o, 64);
  float inv = 0.25f / (s + 1e-16f);
  for (int c = 0; c < nch; ++c) {
    int ei = c * 16 + (lane >> 2);
    if (ei < deg) {
      int sr = rsD[j0 + ei];
      aw[(size_t)(sr >> 3) * 4 + h] *= inv;
    }
  }
}

// W fp32 [L][R][D][HK] -> wt bf16 [L][R][HK][D]  (all layers, z = l*R+r)
__global__ void k_cvt_w_all(const float* __restrict__ W, u16* __restrict__ wt) {
  __shared__ u16 tile[64][65];
  const int z = blockIdx.z, k0 = blockIdx.y * 64, c0 = blockIdx.x * 64;
  const int t = threadIdx.x;
  const int tk = t >> 4, tc4 = (t & 15) * 4;
  const float* Wz = W + (size_t)z * D_ * HK_;
  u16* wz = wt + (size_t)z * HK_ * D_;
#pragma unroll
  for (int p = 0; p < 4; ++p) {
    int krow = tk + p * 16;
    const float4 v = *(const float4*)&Wz[(size_t)(k0 + krow) * HK_ + c0 + tc4];
    tile[tc4 + 0][krow] = bfr(v.x);
    tile[tc4 + 1][krow] = bfr(v.y);
    tile[tc4 + 2][krow] = bfr(v.z);
    tile[tc4 + 3][krow] = bfr(v.w);
  }
  __syncthreads();
#pragma unroll
  for (int p = 0; p < 4; ++p) {
    int crow = tk + p * 16;
    uint2 o;
    o.x = (u32)tile[crow][tc4 + 0] | ((u32)tile[crow][tc4 + 1] << 16);
    o.y = (u32)tile[crow][tc4 + 2] | ((u32)tile[crow][tc4 + 3] << 16);
    *(uint2*)&wz[(size_t)(c0 + crow) * D_ + k0 + tc4] = o;
  }
}

// ---------------- edge-GEMM v8d: r15 structure + dst-slot message stores ----------------
__global__ __launch_bounds__(512, 1) void k_edge8(
    const u16* __restrict__ xb, const u16* __restrict__ wt,   // wt: layer base [R][HK][D]
    const int* __restrict__ indptrR, const int* __restrict__ padBase,
    const int* __restrict__ srcR, const int* __restrict__ dstOf,
    const float* __restrict__ aw, u16* __restrict__ m) {
  __shared__ u16 atile[128 * 128];     // 32 KB, XOR-swizzled
  __shared__ u16 outb[128 * 128];      // 32 KB, epilogue staging (no post-MFMA barrier)
  __shared__ float awl[128][4];
  __shared__ int srcl[128];
  __shared__ int dsl[128];
  const int t = threadIdx.x;
  const int b128 = blockIdx.x * 128;
  if (b128 >= padBase[R_]) return;     // block-uniform tail guard
  int r = 0;
  while (b128 >= padBase[r + 1]) ++r;  // block-uniform, <=8 iters
  const int ip0 = indptrR[r * N_];
  const int cnt = indptrR[(r + 1) * N_] - ip0;
  const int local0 = b128 - padBase[r];
  const u16* wrp = wt + (size_t)r * HK_ * D_;
  const int wid = t >> 6, lane = t & 63;
  const int l15 = lane & 15, l4 = lane >> 4;
  // B-frags issued FIRST (L2-hot; latency overlaps meta + A-gather)
  short8 breg[4][4];                   // [ks][h]
#pragma unroll
  for (int ks = 0; ks < 4; ++ks)
#pragma unroll
    for (int h = 0; h < 4; ++h) {
      int c = (wid + 8 * h) * 16 + l15;
      breg[ks][h] = *(const short8*)(wrp + (size_t)c * 128 + ks * 32 + l4 * 8);
    }
  // meta (rel-sorted slots: coalesced)
  if (t < 128) {
    int lidx = local0 + t;
    if (lidx < cnt) {
      srcl[t] = srcR[ip0 + lidx];
      dsl[t] = dstOf[ip0 + lidx];
      *(float4*)awl[t] = *(const float4*)(aw + (size_t)(ip0 + lidx) * 4);
    } else {
      srcl[t] = 0;
      dsl[t] = -1;
      *(float4*)awl[t] = make_float4(0.f, 0.f, 0.f, 0.f);
    }
  }
  __syncthreads();   // meta visible
  // A gather -> LDS (4 uint4/thread; 16 lanes per row)
#pragma unroll
  for (int p = 0; p < 4; ++p) {
    int idx = t + p * 512;
    int row = idx >> 4, seg = idx & 15;
    uint4 v = *(const uint4*)(xb + (size_t)srcl[row] * 128 + seg * 8);
    *(uint4*)((char*)atile + row * 256 + ((seg * 16) ^ ((row & 7) << 4))) = v;
  }
  __syncthreads();   // A visible
  // MFMA: 128 rows x 16 out-cols (4 orig colfrags) x K=128 -> 128 MFMA/wave
  f32x4 acc[8][4];                     // [row i][h]
#pragma unroll
  for (int i = 0; i < 8; ++i)
#pragma unroll
    for (int h = 0; h < 4; ++h) acc[i][h] = (f32x4){0.f, 0.f, 0.f, 0.f};
#pragma unroll
  for (int ks = 0; ks < 4; ++ks) {
    short8 av[8];
#pragma unroll
    for (int i = 0; i < 8; ++i) {
      int row = i * 16 + l15;
      av[i] = *(const short8*)((char*)atile + row * 256 +
                ((l4 * 16 + ks * 64) ^ ((row & 7) << 4)));
    }
#pragma unroll
    for (int i = 0; i < 8; ++i)
#pragma unroll
      for (int h = 0; h < 4; ++h)
        // swapped operands: lane holds row = i*16+l15, cols (wid+8h)*16 + l4*4 + rg
        acc[i][h] = __builtin_amdgcn_mfma_f32_16x16x32_bf16(breg[ks][h], av[i],
                                                            acc[i][h], 0, 0, 0);
  }
  // epilogue phase A: head-reduce -> outb (separate region: no barrier needed here)
#pragma unroll
  for (int i = 0; i < 8; ++i) {
    int row = i * 16 + l15;
    const float4 awf = *(const float4*)awl[row];
    float v0 = awf.x * acc[i][0][0] + awf.y * acc[i][1][0] + awf.z * acc[i][2][0] + awf.w * acc[i][3][0];
    float v1 = awf.x * acc[i][0][1] + awf.y * acc[i][1][1] + awf.z * acc[i][2][1] + awf.w * acc[i][3][1];
    float v2 = awf.x * acc[i][0][2] + awf.y * acc[i][1][2] + awf.z * acc[i][2][2] + awf.w * acc[i][3][2];
    float v3 = awf.x * acc[i][0][3] + awf.y * acc[i][1][3] + awf.z * acc[i][2][3] + awf.w * acc[i][3][3];
    uint2 o;
    o.x = (u32)bfr(v0) | ((u32)bfr(v1) << 16);
    o.y = (u32)bfr(v2) | ((u32)bfr(v3) << 16);
    *(uint2*)((char*)outb + row * 256 + ((wid * 32 + l4 * 8) ^ ((row & 7) << 4))) = o;
  }
  __syncthreads();   // outb complete across waves
  // phase B: full-line stores to dst-slot rows (256B contiguous per row)
  {
    int row = t >> 2, c0 = (t & 3) * 64;   // byte offsets within 256B row
    int slot = dsl[row];
    if (slot >= 0) {
      char* gout = (char*)(m + (size_t)slot * 128) + c0;
#pragma unroll
      for (int qq = 0; qq < 4; ++qq) {
        uint4 v = *(const uint4*)((char*)outb + row * 256 + ((c0 + qq * 16) ^ ((row & 7) << 4)));
        *(uint4*)(gout + qq * 16) = v;
      }
    }
  }
}

// ---------------- fused: aggregate (dst-contiguous rows) + bias/relu + x/xb + next q,k ----------------
__global__ __launch_bounds__(256) void k_aggqk(
    const int* __restrict__ ipN, const u16* __restrict__ m,
    const float* __restrict__ Bl, const float* __restrict__ WQK, int doqk,
    float* __restrict__ xout, u16* __restrict__ xbout,
    float* __restrict__ q, float* __restrict__ kk) {
  __shared__ float wqs[128 * 64];      // 32 KB
  __shared__ float xrow[4][128];
  const int t = threadIdx.x;
  if (doqk) {
#pragma unroll
    for (int p = 0; p < 8; ++p)
      *(float4*)&wqs[(t + p * 256) * 4] = *(const float4*)&WQK[(t + p * 256) * 4];
  }
  const int w = t >> 6;
  int n = blockIdx.x * 4 + w;
  int lane = t & 63;
  int j0 = ipN[n], j1 = ipN[n + 1];
  float s0 = 0.f, s1 = 0.f;   // d = 2*lane, 2*lane+1
  int j = j0;
  for (; j + 1 < j1; j += 2) {          // contiguous rows; 2-wide load ILP
    u32 v0 = *((const u32*)(m + (size_t)j * 128) + lane);
    u32 v1 = *((const u32*)(m + (size_t)(j + 1) * 128) + lane);
    s0 += bf2f(v0 & 0xffffu) + bf2f(v1 & 0xffffu);
    s1 += bf2f(v0 >> 16) + bf2f(v1 >> 16);
  }
  if (j < j1) {
    u32 v0 = *((const u32*)(m + (size_t)j * 128) + lane);
    s0 += bf2f(v0 & 0xffffu);
    s1 += bf2f(v0 >> 16);
  }
  float2 o;
  o.x = fmaxf(s0 + Bl[2 * lane], 0.f);
  o.y = fmaxf(s1 + Bl[2 * lane + 1], 0.f);
  *((float2*)(xout + (size_t)n * D_) + lane) = o;
  ((u32*)(xbout + (size_t)n * D_))[lane] = (u32)bfr(o.x) | ((u32)bfr(o.y) << 16);
  if (doqk) {
    xrow[w][2 * lane] = o.x;
    xrow[w][2 * lane + 1] = o.y;
    __syncthreads();   // wqs + xrow visible (doqk is uniform kernel arg)
    const float* xr = xrow[w];
    float s = 0.f;
#pragma unroll
    for (int d4 = 0; d4 < 32; ++d4) {
      const float4 xv = *(const float4*)&xr[d4 * 4];
      s += xv.x * wqs[(d4 * 4 + 0) * 64 + lane] + xv.y * wqs[(d4 * 4 + 1) * 64 + lane] +
           xv.z * wqs[(d4 * 4 + 2) * 64 + lane] + xv.w * wqs[(d4 * 4 + 3) * 64 + lane];
    }
    if (lane < 32) q[(size_t)n * 32 + lane] = s;
    else           kk[(size_t)n * 32 + (lane - 32)] = s;
  }
}

// ---------------- graph mean-pool ----------------
__global__ void k_pool(const float* __restrict__ x, float* __restrict__ pooled) {
  int i = blockIdx.x * blockDim.x + threadIdx.x; // G*D
  if (i >= G_ * D_) return;
  int d = i & 127, g = i >> 7;
  float s = 0.f;
  for (int j = 0; j < NPG_; ++j) s += x[(size_t)(g * NPG_ + j) * D_ + d];
  pooled[i] = s * (1.0f / NPG_);
}

// ---------------- head MLP ----------------
__global__ void k_head(const float* __restrict__ pooled, const float* __restrict__ fc1w,
                       const float* __restrict__ fc1b, const float* __restrict__ polw,
                       const float* __restrict__ polb, const float* __restrict__ valw,
                       const float* __restrict__ valb, float* __restrict__ out) {
  int g = blockIdx.x;
  int t = threadIdx.x; // 64
  __shared__ float hb[64];
  const float* p = pooled + (size_t)g * D_;
  float s = fc1b[t];
  for (int d = 0; d < D_; ++d) s += p[d] * fc1w[d * 64 + t];
  hb[t] = fmaxf(s, 0.f);
  __syncthreads();
  if (t < 7) {
    float s2 = polb[t];
    for (int j = 0; j < 64; ++j) s2 += hb[j] * polw[j * 7 + t];
    out[g * 7 + t] = s2;
  } else if (t == 7) {
    float s2 = valb[0];
    for (int j = 0; j < 64; ++j) s2 += hb[j] * valw[j];
    out[G_ * 7 + g] = tanhf(s2);
  }
}

extern "C" void kernel_launch(void* const* d_in, const int* in_sizes, int n_in,
                              void* d_out, int out_size, void* d_ws, size_t ws_size,
                              hipStream_t stream) {
  (void)in_sizes; (void)n_in; (void)out_size;
  const int*   x_nodes = (const int*)d_in[0];
  const int*   eidx    = (const int*)d_in[1];
  const int*   etype   = (const int*)d_in[2];
  const float* emb     = (const float*)d_in[4];
  const float* W       = (const float*)d_in[5];
  const float* Q       = (const float*)d_in[6];
  const float* Km      = (const float*)d_in[7];
  const float* B       = (const float*)d_in[8];
  const float* fc1w    = (const float*)d_in[9];
  const float* fc1b    = (const float*)d_in[10];
  const float* polw    = (const float*)d_in[11];
  const float* polb    = (const float*)d_in[12];
  const float* valw    = (const float*)d_in[13];
  const float* valb    = (const float*)d_in[14];
  float* out = (float*)d_out;
  const int* srcA = eidx;        // edge_index[0,:]
  const int* dstA = eidx + E_;   // edge_index[1,:]

  char* p = (char*)d_ws;
  size_t used = 0;
  auto carve = [&](size_t bytes) {
    char* q = p;
    size_t adv = (bytes + 255) & ~(size_t)255;
    p += adv;
    used += adv;
    return q;
  };
  float* x_cur  = (float*)carve((size_t)N_ * D_ * 4);            // 10.5 MB
  float* x_nxt  = (float*)carve((size_t)N_ * D_ * 4);            // 10.5 MB
  u16*   xbf    = (u16*)carve((size_t)N_ * D_ * 2);              // 5.2 MB
  u16*   mbuf   = (u16*)carve((size_t)E_ * D_ * 2);              // 41.9 MB (exact E rows)
  float* qbuf   = (float*)carve((size_t)N_ * 32 * 4);            // 2.6 MB
  float* kbuf   = (float*)carve((size_t)N_ * 32 * 4);            // 2.6 MB
  float* awbuf  = (float*)carve((size_t)E_ * H_ * 4);            // 2.6 MB
  float* WQKb   = (float*)carve((size_t)L_ * D_ * 64 * 4);       // 131 KB
  u16*   Wtb    = (u16*)carve((size_t)L_ * R_ * HK_ * D_ * 2);   // 4.2 MB
  float* pooled = (float*)carve((size_t)G_ * D_ * 4);
  int* countsR  = (int*)carve((size_t)R_ * N_ * 4);
  int* cursorR  = (int*)carve((size_t)R_ * N_ * 4);
  int* indptrR  = (int*)carve((size_t)(R_ * N_ + 1) * 4);
  int* srcR     = (int*)carve((size_t)E_ * 4);
  int* dstOf    = (int*)carve((size_t)E_ * 4);
  int* srcD     = (int*)carve((size_t)E_ * 4);
  int* rsD      = (int*)carve((size_t)E_ * 4);
  int* countsN  = (int*)carve((size_t)N_ * 4);
  int* cursorN  = (int*)carve((size_t)N_ * 4);
  int* indptrN  = (int*)carve((size_t)(N_ + 1) * 4);
  int* padBase  = (int*)carve((size_t)(R_ + 1) * 4);
  int* bsumR    = (int*)carve((size_t)160 * 4);
  int* bsumN    = (int*)carve((size_t)32 * 4);
  if (used > ws_size) return;  // defensive: fail via poisoned output, not OOB crash

  constexpr int RN = R_ * N_;          // 163840
  constexpr int EDGE_BLOCKS = E_ / 128 + R_;  // 1288 (covers padding)

  // ---- fused CSR builds + one-time precomputes (9 setup dispatches) ----
  k_zero2<<<(RN + N_ + 255) / 256, 256, 0, stream>>>(countsR, countsN);
  k_count_both<<<E_ / 256, 256, 0, stream>>>(dstA, etype, countsR, countsN);
  k_bsum2<<<180, 256, 0, stream>>>(countsR, countsN, bsumR, bsumN);
  k_bscan2<<<1, 256, 0, stream>>>(bsumR, bsumN, indptrR + RN, indptrN + N_, padBase);
  k_scan32<<<180, 256, 0, stream>>>(countsR, countsN, bsumR, bsumN,
                                    indptrR, cursorR, indptrN, cursorN);
  k_scatter_both<<<E_ / 256, 256, 0, stream>>>(dstA, etype, srcA, cursorR, cursorN,
                                               srcR, dstOf, srcD, rsD);
  k_wqk_all<<<(L_ * R_ * D_ * 64) / 256, 256, 0, stream>>>(W, Q, Km, WQKb);
  k_cvt_w_all<<<dim3(HK_ / 64, D_ / 64, L_ * R_), 256, 0, stream>>>(W, Wtb);
  k_embed_qk<<<N_ / 32, 256, 0, stream>>>(x_nodes, emb, WQKb, x_cur, xbf, qbuf, kbuf);

  for (int l = 0; l < L_; ++l) {
    const float* Bl = B + (size_t)l * D_;
    k_attn<<<N_ / 4, 256, 0, stream>>>(indptrN, srcD, rsD, qbuf, kbuf, awbuf);
    k_edge8<<<EDGE_BLOCKS, 512, 0, stream>>>(xbf, Wtb + (size_t)l * R_ * HK_ * D_,
                                             indptrR, padBase, srcR, dstOf, awbuf, mbuf);
    int doqk = (l < L_ - 1) ? 1 : 0;
    k_aggqk<<<N_ / 4, 256, 0, stream>>>(indptrN, mbuf, Bl,
                                        WQKb + (size_t)(l + 1) * D_ * 64 * (doqk ? 1 : 0),
                                        doqk, x_nxt, xbf, qbuf, kbuf);
    float* tmp = x_cur; x_cur = x_nxt; x_nxt = tmp;
  }

  k_pool<<<(G_ * D_) / 256, 256, 0, stream>>>(x_cur, pooled);
  k_head<<<G_, 64, 0, stream>>>(pooled, fc1w, fc1b, polw, polb, valw, valb, out);
}